// Round 14
// baseline (2382.415 us; speedup 1.0000x reference)
//
#include <hip/hip_runtime.h>
#include <hip/hip_bf16.h>
#include <math.h>

namespace {

constexpr int BB = 8;
constexpr int LL = 768;
constexpr int DD = 512;
constexpr int L2E = LL * LL;
constexpr int LDIAG = L2E + 8192;
constexpr float NEGF = -1e9f;

typedef __attribute__((ext_vector_type(8))) short bf16x8;
typedef __attribute__((ext_vector_type(8))) unsigned short u16x8;
typedef __attribute__((ext_vector_type(4))) float f32x4;

__device__ __forceinline__ float softplus_f(float x) {
  return x > 0.f ? x + log1pf(expf(-x)) : log1pf(expf(x));
}
__device__ __forceinline__ float logsigmoid_f(float x) {
  return x > 0.f ? -log1pf(expf(-x)) : x - log1pf(expf(x));
}

__device__ __forceinline__ float bf_lo(unsigned u) { return __uint_as_float(u << 16); }
__device__ __forceinline__ float bf_hi(unsigned u) { return __uint_as_float(u & 0xffff0000u); }

__device__ __forceinline__ int lofs(int s) { return (s > LL - 1) ? (s - (LL - 1)) : 0; }

__device__ __forceinline__ int Dmap(int s) {
  if (s <= LL - 1) {
    const int m = s >> 2, i = s & 3;
    const int c = (i == 0) ? 4 : (i == 1) ? 8 : (i == 2) ? 16 : 24;
    return 8 * m * m + (20 + 4 * i) * m + c;
  }
  const int q = (s - LL) >> 2, i = (s - LL) & 3;
  const int base = 298757 + 3092 * q - 8 * q * q;
  const int off = (i == 0) ? 0 : (i == 1) ? (773 - 4 * q)
                : (i == 2) ? (1546 - 8 * q) : (2315 - 12 * q);
  return base + off;
}
__device__ __forceinline__ int dDa(int s) {
  if (s < LL - 1) return s + 4 + ((-s) & 3);
  if (s == LL - 1) return 773;
  return 1539 - s + ((s + 2) & 3);
}
__device__ __forceinline__ int dIa(int s) { return dDa(s) - ((s >= LL - 1) ? 1 : 0); }

// -------- fp32 -> bf16 convert --------
__global__ __launch_bounds__(256) void tobf16(
    const float* __restrict__ src, unsigned short* __restrict__ dst, int n) {
  const int i = (blockIdx.x * 256 + threadIdx.x) * 4;
  if (i < n) {
    const float4 v = *(const float4*)(src + i);
    ushort4 o;
    o.x = __bfloat16_as_ushort(__float2bfloat16(v.x));
    o.y = __bfloat16_as_ushort(__float2bfloat16(v.y));
    o.z = __bfloat16_as_ushort(__float2bfloat16(v.z));
    o.w = __bfloat16_as_ushort(__float2bfloat16(v.w));
    *(ushort4*)(dst + i) = o;
  }
}

// -------- MFMA GEMM 1 --------
__global__ __launch_bounds__(256) void mfma_linear(
    const unsigned short* __restrict__ Xb, const unsigned short* __restrict__ Wb,
    const float* __restrict__ bm, const float* __restrict__ bg,
    unsigned short* __restrict__ Zb) {
  __shared__ unsigned short As[128][32];
  __shared__ unsigned short Bs[128][32];
  const int which = blockIdx.z;
  const unsigned short* X = Xb + (size_t)(which & 1) * (6144 * 512);
  const unsigned short* W = Wb + (size_t)(which >> 1) * (512 * 512);
  const float* bias = (which >= 2) ? bg : bm;
  unsigned short* out = Zb + (size_t)which * (6144 * 512);
  const int row0 = blockIdx.y * 128, col0 = blockIdx.x * 128;
  const int t = threadIdx.x, wv = t >> 6, l = t & 63;
  const int wm = (wv >> 1) * 64, wn = (wv & 1) * 64;

  f32x4 acc[4][4] = {};
  for (int k0 = 0; k0 < 512; k0 += 32) {
#pragma unroll
    for (int c = t; c < 512; c += 256) {
      const int rowi = c >> 2, seg = (c & 3) << 3;
      *(u16x8*)&As[rowi][seg] = *(const u16x8*)&X[(size_t)(row0 + rowi) * 512 + k0 + seg];
      *(u16x8*)&Bs[rowi][seg] = *(const u16x8*)&W[(size_t)(col0 + rowi) * 512 + k0 + seg];
    }
    __syncthreads();
    bf16x8 af[4], bfr[4];
#pragma unroll
    for (int f = 0; f < 4; ++f) {
      af[f]  = *(const bf16x8*)&As[wm + f * 16 + (l & 15)][(l >> 4) << 3];
      bfr[f] = *(const bf16x8*)&Bs[wn + f * 16 + (l & 15)][(l >> 4) << 3];
    }
#pragma unroll
    for (int fm = 0; fm < 4; ++fm)
#pragma unroll
      for (int fn = 0; fn < 4; ++fn)
        acc[fm][fn] = __builtin_amdgcn_mfma_f32_16x16x32_bf16(
            af[fm], bfr[fn], acc[fm][fn], 0, 0, 0);
    __syncthreads();
  }
#pragma unroll
  for (int fm = 0; fm < 4; ++fm) {
    const int rbase = row0 + wm + fm * 16 + ((l >> 4) << 2);
#pragma unroll
    for (int fn = 0; fn < 4; ++fn) {
      const int col = col0 + wn + fn * 16 + (l & 15);
      const float bv = bias[col];
      const f32x4 v = acc[fm][fn];
#pragma unroll
      for (int j = 0; j < 4; ++j)
        out[(size_t)(rbase + j) * 512 + col] =
            __bfloat16_as_ushort(__float2bfloat16(v[j] + bv));
    }
  }
}

// -------- MFMA GEMM 2 --------
__global__ __launch_bounds__(256) void mfma_logits(
    const unsigned short* __restrict__ Zb,
    float* __restrict__ theta, float* __restrict__ Aout) {
  __shared__ unsigned short As[128][32];
  __shared__ unsigned short Bs[128][32];
  const int bz = blockIdx.z;
  const int b = bz >> 1, w = bz & 1;
  const unsigned short* X = Zb + (size_t)(w ? 2 : 0) * (6144 * 512) + (size_t)b * (768 * 512);
  const unsigned short* Y = Zb + (size_t)(w ? 3 : 1) * (6144 * 512) + (size_t)b * (768 * 512);
  float* out = (w ? Aout : theta) + (size_t)b * L2E;
  const int row0 = blockIdx.y * 128, col0 = blockIdx.x * 128;
  const int t = threadIdx.x, wv = t >> 6, l = t & 63;
  const int wm = (wv >> 1) * 64, wn = (wv & 1) * 64;

  f32x4 acc[4][4] = {};
  for (int k0 = 0; k0 < 512; k0 += 32) {
#pragma unroll
    for (int c = t; c < 512; c += 256) {
      const int rowi = c >> 2, seg = (c & 3) << 3;
      *(u16x8*)&As[rowi][seg] = *(const u16x8*)&X[(size_t)(row0 + rowi) * 512 + k0 + seg];
      *(u16x8*)&Bs[rowi][seg] = *(const u16x8*)&Y[(size_t)(col0 + rowi) * 512 + k0 + seg];
    }
    __syncthreads();
    bf16x8 af[4], bfr[4];
#pragma unroll
    for (int f = 0; f < 4; ++f) {
      af[f]  = *(const bf16x8*)&As[wm + f * 16 + (l & 15)][(l >> 4) << 3];
      bfr[f] = *(const bf16x8*)&Bs[wn + f * 16 + (l & 15)][(l >> 4) << 3];
    }
#pragma unroll
    for (int fm = 0; fm < 4; ++fm)
#pragma unroll
      for (int fn = 0; fn < 4; ++fn)
        acc[fm][fn] = __builtin_amdgcn_mfma_f32_16x16x32_bf16(
            af[fm], bfr[fn], acc[fm][fn], 0, 0, 0);
    __syncthreads();
  }
#pragma unroll
  for (int fm = 0; fm < 4; ++fm) {
    const int rbase = row0 + wm + fm * 16 + ((l >> 4) << 2);
#pragma unroll
    for (int fn = 0; fn < 4; ++fn) {
      const int col = col0 + wn + fn * 16 + (l & 15);
      const f32x4 v = acc[fm][fn];
#pragma unroll
      for (int j = 0; j < 4; ++j)
        out[(size_t)(rbase + j) * LL + col] = w ? logsigmoid_f(v[j]) : softplus_f(v[j]);
    }
  }
}

// -------- row-major theta,A -> packed bf16x2 compact-aligned diag --------
__global__ __launch_bounds__(256) void row2diag(
    const float* __restrict__ theta, const float* __restrict__ A,
    unsigned* __restrict__ TAc) {
  __shared__ float tT[64 * 66];
  __shared__ float tA[64 * 66];
  const int b = blockIdx.z;
  const float* inT = theta + (size_t)b * L2E;
  const float* inA = A + (size_t)b * L2E;
  unsigned* out = TAc + (size_t)b * LDIAG;
  const int r0 = blockIdx.y * 64, c0 = blockIdx.x * 64;
  const int t = threadIdx.x, lane = t & 63, grp = t >> 6;
  for (int it = 0; it < 16; ++it) {
    const int rr = it * 4 + grp;
    tT[rr * 66 + lane] = inT[(size_t)(r0 + rr) * LL + c0 + lane];
    tA[rr * 66 + lane] = inA[(size_t)(r0 + rr) * LL + c0 + lane];
  }
  __syncthreads();
  for (int si = grp; si < 127; si += 4) {
    const int s = r0 + c0 + si;
    const int rlo = max(r0, s - c0 - 63);
    const int rhi = min(r0 + 63, s - c0);
    const int base = Dmap(s) - lofs(s);
    const int r = rlo + lane;
    if (r <= rhi) {
      const int ii = (r - r0) * 66 + (s - r - c0);
      const unsigned ut = __bfloat16_as_ushort(__float2bfloat16(tT[ii]));
      const unsigned ua = __bfloat16_as_ushort(__float2bfloat16(tA[ii]));
      out[base + r] = (ua << 16) | ut;
    }
  }
}

// -------- compact-aligned bf16 E -> row-major fp32 (aln) --------
__global__ __launch_bounds__(256) void diag2row(
    const unsigned short* __restrict__ Edc, float* __restrict__ aln) {
  __shared__ float tile[64 * 66];
  const int b = blockIdx.z;
  const int r0 = blockIdx.y * 64;
  const int c0 = blockIdx.x * 64;
  const unsigned short* E = Edc + (size_t)b * LDIAG;
  float* out = aln + (size_t)b * L2E;
  const int t = threadIdx.x;
  const int lane = t & 63;
  const int grp = t >> 6;
  for (int si = grp; si < 127; si += 4) {
    const int s = r0 + c0 + si;
    const int rlo = max(r0, s - c0 - 63);
    const int rhi = min(r0 + 63, s - c0);
    const int base = Dmap(s) - lofs(s);
    const int r = rlo + lane;
    if (r <= rhi) {
      tile[(r - r0) * 66 + (s - r - c0)] =
          __uint_as_float(((unsigned)E[base + r]) << 16);
    }
  }
  __syncthreads();
  for (int it = 0; it < 16; ++it) {
    const int rr = it * 4 + grp;
    out[(size_t)(r0 + rr) * LL + c0 + lane] = tile[rr * 66 + lane];
  }
}

__device__ __forceinline__ void lds_release_store(int* p, int v) {
  asm volatile("s_waitcnt lgkmcnt(0)" ::: "memory");
  __hip_atomic_store(p, v, __ATOMIC_RELAXED, __HIP_MEMORY_SCOPE_WORKGROUP);
}

// -------- NW forward: 4 batches/block (12 waves/CU), named-register slots ----
__global__ __launch_bounds__(768, 1) void nw_fwd(
    const unsigned* __restrict__ TAc, float* __restrict__ Vr) {
  __shared__ int Pf[4][4];
  __shared__ float BvF[4][2][1024];

  const int bi = threadIdx.x / 192;
  const int tl = threadIdx.x - bi * 192;
  const int b = blockIdx.x * 4 + bi;
  const unsigned* TA = TAc + (size_t)b * LDIAG;
  float* V = Vr + (size_t)b * (1536 * LL);

  const int w = tl >> 6, l = tl & 63;
  const int rowb = 4 * tl;
  const int kb = 256 * w + 2;

  if (tl < 4) Pf[bi][tl] = 0;
  __syncthreads();

  uint4 q0, q1, q2, q3;
  {
    int s0;
    s0 = kb - 2; q2 = *(const uint4*)(TA + (Dmap(s0) + rowb - lofs(s0)));
    s0 = kb - 1; q3 = *(const uint4*)(TA + (Dmap(s0) + rowb - lofs(s0)));
    s0 = kb;     q0 = *(const uint4*)(TA + (Dmap(s0) + rowb - lofs(s0)));
    s0 = kb + 1; q1 = *(const uint4*)(TA + (Dmap(s0) + rowb - lofs(s0)));
  }
  int sL = kb + 2;
  int iL = Dmap(sL) + rowb - lofs(sL);
  int iS4 = (kb - 2) * LL + rowb;
  float4 p1 = make_float4(NEGF, NEGF, NEGF, NEGF);
  float4 p2 = p1;
  float rvh = NEGF;
  float pv3 = NEGF;

#define FSTEP(U, Q) { \
  const int k = kg + (U); \
  float rv = __shfl_up(pv3, 1); \
  if (l == 0) rv = (w == 0) ? NEGF : BvF[bi][w - 1][min(k - kb + 255, 1023)]; \
  float rdg = rvh; \
  if (l == 0 && w == 0) rdg = (k == 2) ? 0.f : NEGF; \
  const int d = k - rowb - 2; \
  float4 vv; \
  { const float av = bf_hi(Q.x), tv = bf_lo(Q.x); \
    const float lft = av + p1.x, up = av + rv; \
    const float mx = fmaxf(rdg, fmaxf(lft, up)); \
    const float val = tv + mx + __logf(__expf(rdg - mx) + __expf(lft - mx) + __expf(up - mx)); \
    vv.x = ((unsigned)d <= 767u) ? val : NEGF; } \
  { const float av = bf_hi(Q.y), tv = bf_lo(Q.y); \
    const float lft = av + p1.y, up = av + p1.x; \
    const float mx = fmaxf(p2.x, fmaxf(lft, up)); \
    const float val = tv + mx + __logf(__expf(p2.x - mx) + __expf(lft - mx) + __expf(up - mx)); \
    vv.y = ((unsigned)(d - 1) <= 767u) ? val : NEGF; } \
  { const float av = bf_hi(Q.z), tv = bf_lo(Q.z); \
    const float lft = av + p1.z, up = av + p1.y; \
    const float mx = fmaxf(p2.y, fmaxf(lft, up)); \
    const float val = tv + mx + __logf(__expf(p2.y - mx) + __expf(lft - mx) + __expf(up - mx)); \
    vv.z = ((unsigned)(d - 2) <= 767u) ? val : NEGF; } \
  { const float av = bf_hi(Q.w), tv = bf_lo(Q.w); \
    const float lft = av + p1.w, up = av + p1.z; \
    const float mx = fmaxf(p2.z, fmaxf(lft, up)); \
    const float val = tv + mx + __logf(__expf(p2.z - mx) + __expf(lft - mx) + __expf(up - mx)); \
    vv.w = ((unsigned)(d - 3) <= 767u) ? val : NEGF; } \
  Q = *(const uint4*)(TA + iL); \
  iL += dIa(sL); ++sL; \
  *(float4*)(V + iS4) = vv; \
  iS4 += LL; \
  if (l == 63 && w < 2) BvF[bi][w][k - kb] = vv.w; \
  pv3 = vv.w; \
  rvh = rv; \
  p2 = p1; p1 = vv; \
}

  for (int kg = kb; kg < kb + 1024; kg += 8) {
    if (l == 0 && w > 0 && kg < kb + 768) {
      const int need = min(kg + 6, kb + 766);
      while (__hip_atomic_load(&Pf[bi][w - 1], __ATOMIC_ACQUIRE,
                               __HIP_MEMORY_SCOPE_WORKGROUP) < need) {}
    }
    FSTEP(0, q2) FSTEP(1, q3) FSTEP(2, q0) FSTEP(3, q1)
    FSTEP(4, q2) FSTEP(5, q3) FSTEP(6, q0) FSTEP(7, q1)
    if (l == 63 && w < 2) lds_release_store(&Pf[bi][w], kg + 7);
  }
#undef FSTEP
}

// -------- NW backward: 4 batches/block (12 waves/CU), named-register slots ---
__global__ __launch_bounds__(768, 1) void nw_bwd(
    const unsigned* __restrict__ TAc, const float* __restrict__ Vr,
    unsigned short* __restrict__ Edc) {
  __shared__ int Pb[4][4];
  __shared__ float Bv2[4][2][1024];
  __shared__ float Be2[4][2][1024];

  const int bi = threadIdx.x / 192;
  const int tl = threadIdx.x - bi * 192;
  const int b = blockIdx.x * 4 + bi;
  const unsigned* TA = TAc + (size_t)b * LDIAG;
  const float* V = Vr + (size_t)b * (1536 * LL);
  unsigned short* Eo = Edc + (size_t)b * LDIAG;

  const int w = tl >> 6, l = tl & 63;
  const int rowb = 4 * tl;
  const int kb = 256 * w + 2;
  const int ke = kb + 1023;

  if (tl < 4) Pb[bi][tl] = 0x7fffffff;
  __syncthreads();

  float4 V0, V1, V2, V3;
  uint4 K0, K1, K2, K3;
  unsigned F0, F1, F2, F3;
  {
    int sv, sk, ik;
    sv = ke - 2; V1 = *(const float4*)(V + (sv * LL + rowb));
    sk = ke - 1; ik = Dmap(sk) + rowb - lofs(sk);
    K1 = *(const uint4*)(TA + ik); F1 = TA[ik + 4];
    sv = ke - 3; V0 = *(const float4*)(V + (sv * LL + rowb));
    sk = ke - 2; ik = Dmap(sk) + rowb - lofs(sk);
    K0 = *(const uint4*)(TA + ik); F0 = TA[ik + 4];
    sv = ke - 4; V3 = *(const float4*)(V + (sv * LL + rowb));
    sk = ke - 3; ik = Dmap(sk) + rowb - lofs(sk);
    K3 = *(const uint4*)(TA + ik); F3 = TA[ik + 4];
    sv = ke - 5; V2 = *(const float4*)(V + (sv * LL + rowb));
    sk = ke - 4; ik = Dmap(sk) + rowb - lofs(sk);
    K2 = *(const uint4*)(TA + ik); F2 = TA[ik + 4];
  }
  int iV = (ke - 6) * LL + rowb;
  int sK1s = ke - 5;
  int iK1 = Dmap(sK1s) + rowb - lofs(sK1s);
  float4 T0, T1;
  {
    const int j0 = Dmap(ke) + rowb - lofs(ke);
    T0 = make_float4(bf_lo(TA[j0 + 1]), bf_lo(TA[j0 + 2]),
                     bf_lo(TA[j0 + 3]), bf_lo(TA[j0 + 4]));
    T1 = make_float4(0.f, 0.f, 0.f, 0.f);
  }
  int sE = ke - 2;
  int iE = Dmap(sE) + rowb - lofs(sE);
  float4 n1v = {}, n1e = {}, n2v = {}, n2e = {}, hv = {}, he = {};
  float pv0 = 0.f, pe0 = 0.f;

#define BCELL(VCr, DO, ILT, N2Vr, N2Er, TKr, S1a, S1b, N1Vr, N1Er, HVr, HEr, OUT) { \
  const bool ok  = (unsigned)(d - (DO)) <= 767u; \
  const bool jlt = (d - (DO)) < 767; \
  float acc = 0.f; \
  if ((ILT) && jlt) acc += N2Er * __expf(VCr - N2Vr + TKr); \
  if (jlt)          acc += HEr * __expf(bf_hi(S1a) + VCr - HVr + bf_lo(S1a)); \
  if ((ILT))        acc += N1Er * __expf(bf_hi(S1b) + VCr - N1Vr + bf_lo(S1b)); \
  OUT = ok ? acc : 0.f; }

#define BSTEP(U, SV, SK, SF, TRD, TWR) { \
  const int k = kg - (U); \
  { float nv3 = __shfl_down(pv0, 1); \
    float ne3 = __shfl_down(pe0, 1); \
    if (l == 63) { \
      if (w < 2) { const int bi2 = min(ke - k + 255, 1023); nv3 = Bv2[bi][w][bi2]; ne3 = Be2[bi][w][bi2]; } \
      else { nv3 = 0.f; ne3 = 0.f; } } \
    n1v.w = nv3; n1e.w = ne3; } \
  const int d = k - rowb - 2; \
  unsigned fifth = __shfl_down(SK.x, 1); \
  if (l == 63) fifth = SF; \
  const float4 vc = SV; \
  float4 ev; \
  BCELL(vc.x, 0, true, n2v.x, n2e.x, TRD.x, SK.x, SK.y, n1v.x, n1e.x, hv.x, he.x, ev.x) \
  BCELL(vc.y, 1, true, n2v.y, n2e.y, TRD.y, SK.y, SK.z, n1v.y, n1e.y, hv.y, he.y, ev.y) \
  BCELL(vc.z, 2, true, n2v.z, n2e.z, TRD.z, SK.z, SK.w, n1v.z, n1e.z, hv.z, he.z, ev.z) \
  BCELL(vc.w, 3, (tl != 191), n2v.w, n2e.w, TRD.w, SK.w, fifth, n1v.w, n1e.w, hv.w, he.w, ev.w) \
  if (k == 2 * LL && tl == 191) ev.w = 1.f; \
  TWR.x = bf_lo(SK.y); TWR.y = bf_lo(SK.z); TWR.z = bf_lo(SK.w); TWR.w = bf_lo(fifth); \
  SV = *(const float4*)(V + max(iV, 0)); \
  iV -= LL; \
  { const int ic = max(iK1, 0); \
    SK = *(const uint4*)(TA + ic); \
    if (l == 63) SF = TA[ic + 4]; \
    iK1 -= dIa(sK1s - 1); --sK1s; } \
  if ((unsigned)d <= 770u) { \
    ushort4 st; \
    st.x = __bfloat16_as_ushort(__float2bfloat16(ev.x)); \
    st.y = __bfloat16_as_ushort(__float2bfloat16(ev.y)); \
    st.z = __bfloat16_as_ushort(__float2bfloat16(ev.z)); \
    st.w = __bfloat16_as_ushort(__float2bfloat16(ev.w)); \
    *(ushort4*)(Eo + iE) = st; } \
  iE -= dIa(sE - 1); --sE; \
  if (l == 0 && w > 0) { Bv2[bi][w - 1][ke - k] = vc.x; Be2[bi][w - 1][ke - k] = ev.x; } \
  pv0 = vc.x; pe0 = ev.x; \
  n2v = n1v; n2e = n1e; \
  n1v.x = vc.y; n1v.y = vc.z; n1v.z = vc.w; \
  n1e.x = ev.y; n1e.y = ev.z; n1e.z = ev.w; \
  hv = vc; he = ev; \
}

  for (int kg = ke; kg > ke - 1024; kg -= 8) {
    if (l == 63 && w < 2 && kg >= kb + 255) {
      const int need = max(kg - 6, kb + 256);
      while (__hip_atomic_load(&Pb[bi][w + 1], __ATOMIC_ACQUIRE,
                               __HIP_MEMORY_SCOPE_WORKGROUP) > need) {}
    }
    BSTEP(0, V1, K1, F1, T0, T1) BSTEP(1, V0, K0, F0, T1, T0)
    BSTEP(2, V3, K3, F3, T0, T1) BSTEP(3, V2, K2, F2, T1, T0)
    BSTEP(4, V1, K1, F1, T0, T1) BSTEP(5, V0, K0, F0, T1, T0)
    BSTEP(6, V3, K3, F3, T0, T1) BSTEP(7, V2, K2, F2, T1, T0)
    if (l == 0 && w > 0) lds_release_store(&Pb[bi][w], kg - 7);
  }
#undef BSTEP
#undef BCELL
}

}  // namespace

extern "C" void kernel_launch(void* const* d_in, const int* in_sizes, int n_in,
                              void* d_out, int out_size, void* d_ws, size_t ws_size,
                              hipStream_t stream) {
  const float* hx = (const float*)d_in[0];
  const float* hy = (const float*)d_in[1];
  const float* Wm = (const float*)d_in[2];
  const float* bm = (const float*)d_in[3];
  const float* Wg = (const float*)d_in[4];
  const float* bg = (const float*)d_in[5];

  float* aln   = (float*)d_out;
  float* theta = aln + (size_t)BB * L2E;
  float* A     = theta + (size_t)BB * L2E;

  unsigned short* hxb = (unsigned short*)d_ws;
  unsigned short* hyb = hxb + (size_t)6144 * 512;
  unsigned short* Wmb = hyb + (size_t)6144 * 512;
  unsigned short* Wgb = Wmb + (size_t)512 * 512;
  unsigned short* Zb  = Wgb + (size_t)512 * 512;
  unsigned* TAc = (unsigned*)d_ws;
  float* Vr = (float*)d_ws + (size_t)BB * LDIAG;
  unsigned short* Edc = (unsigned short*)(Vr + (size_t)BB * (1536 * LL));

  const int nX = 6144 * 512, nW = 512 * 512;
  tobf16<<<(nX / 4 + 255) / 256, 256, 0, stream>>>(hx, hxb, nX);
  tobf16<<<(nX / 4 + 255) / 256, 256, 0, stream>>>(hy, hyb, nX);
  tobf16<<<(nW / 4 + 255) / 256, 256, 0, stream>>>(Wm, Wmb, nW);
  tobf16<<<(nW / 4 + 255) / 256, 256, 0, stream>>>(Wg, Wgb, nW);

  mfma_linear<<<dim3(4, 48, 4), 256, 0, stream>>>(hxb, Wmb, bm, bg, Zb);
  mfma_logits<<<dim3(6, 6, 16), 256, 0, stream>>>(Zb, theta, A);

  row2diag<<<dim3(LL / 64, LL / 64, BB), 256, 0, stream>>>(theta, A, TAc);
  nw_fwd<<<dim3(BB / 4), 768, 0, stream>>>(TAc, Vr);
  nw_bwd<<<dim3(BB / 4), 768, 0, stream>>>(TAc, Vr, Edc);
  diag2row<<<dim3(LL / 64, LL / 64, BB), 256, 0, stream>>>(Edc, aln);
}

// Round 15
// 1981.694 us; speedup vs baseline: 1.2022x; 1.2022x over previous
//
#include <hip/hip_runtime.h>
#include <hip/hip_bf16.h>
#include <math.h>

namespace {

constexpr int BB = 8;
constexpr int LL = 768;
constexpr int DD = 512;
constexpr int L2E = LL * LL;
constexpr int LDIAG = L2E + 8192;
constexpr float NEGF = -1e9f;

typedef __attribute__((ext_vector_type(8))) short bf16x8;
typedef __attribute__((ext_vector_type(8))) unsigned short u16x8;
typedef __attribute__((ext_vector_type(4))) float f32x4;

__device__ __forceinline__ float softplus_f(float x) {
  return x > 0.f ? x + log1pf(expf(-x)) : log1pf(expf(x));
}
__device__ __forceinline__ float logsigmoid_f(float x) {
  return x > 0.f ? -log1pf(expf(-x)) : x - log1pf(expf(x));
}

__device__ __forceinline__ float bf_lo(unsigned u) { return __uint_as_float(u << 16); }
__device__ __forceinline__ float bf_hi(unsigned u) { return __uint_as_float(u & 0xffff0000u); }

__device__ __forceinline__ int lofs(int s) { return (s > LL - 1) ? (s - (LL - 1)) : 0; }

__device__ __forceinline__ int Dmap(int s) {
  if (s <= LL - 1) {
    const int m = s >> 2, i = s & 3;
    const int c = (i == 0) ? 4 : (i == 1) ? 8 : (i == 2) ? 16 : 24;
    return 8 * m * m + (20 + 4 * i) * m + c;
  }
  const int q = (s - LL) >> 2, i = (s - LL) & 3;
  const int base = 298757 + 3092 * q - 8 * q * q;
  const int off = (i == 0) ? 0 : (i == 1) ? (773 - 4 * q)
                : (i == 2) ? (1546 - 8 * q) : (2315 - 12 * q);
  return base + off;
}
__device__ __forceinline__ int dDa(int s) {
  if (s < LL - 1) return s + 4 + ((-s) & 3);
  if (s == LL - 1) return 773;
  return 1539 - s + ((s + 2) & 3);
}
__device__ __forceinline__ int dIa(int s) { return dDa(s) - ((s >= LL - 1) ? 1 : 0); }

// -------- fp32 -> bf16 convert --------
__global__ __launch_bounds__(256) void tobf16(
    const float* __restrict__ src, unsigned short* __restrict__ dst, int n) {
  const int i = (blockIdx.x * 256 + threadIdx.x) * 4;
  if (i < n) {
    const float4 v = *(const float4*)(src + i);
    ushort4 o;
    o.x = __bfloat16_as_ushort(__float2bfloat16(v.x));
    o.y = __bfloat16_as_ushort(__float2bfloat16(v.y));
    o.z = __bfloat16_as_ushort(__float2bfloat16(v.z));
    o.w = __bfloat16_as_ushort(__float2bfloat16(v.w));
    *(ushort4*)(dst + i) = o;
  }
}

// -------- MFMA GEMM 1 --------
__global__ __launch_bounds__(256) void mfma_linear(
    const unsigned short* __restrict__ Xb, const unsigned short* __restrict__ Wb,
    const float* __restrict__ bm, const float* __restrict__ bg,
    unsigned short* __restrict__ Zb) {
  __shared__ unsigned short As[128][32];
  __shared__ unsigned short Bs[128][32];
  const int which = blockIdx.z;
  const unsigned short* X = Xb + (size_t)(which & 1) * (6144 * 512);
  const unsigned short* W = Wb + (size_t)(which >> 1) * (512 * 512);
  const float* bias = (which >= 2) ? bg : bm;
  unsigned short* out = Zb + (size_t)which * (6144 * 512);
  const int row0 = blockIdx.y * 128, col0 = blockIdx.x * 128;
  const int t = threadIdx.x, wv = t >> 6, l = t & 63;
  const int wm = (wv >> 1) * 64, wn = (wv & 1) * 64;

  f32x4 acc[4][4] = {};
  for (int k0 = 0; k0 < 512; k0 += 32) {
#pragma unroll
    for (int c = t; c < 512; c += 256) {
      const int rowi = c >> 2, seg = (c & 3) << 3;
      *(u16x8*)&As[rowi][seg] = *(const u16x8*)&X[(size_t)(row0 + rowi) * 512 + k0 + seg];
      *(u16x8*)&Bs[rowi][seg] = *(const u16x8*)&W[(size_t)(col0 + rowi) * 512 + k0 + seg];
    }
    __syncthreads();
    bf16x8 af[4], bfr[4];
#pragma unroll
    for (int f = 0; f < 4; ++f) {
      af[f]  = *(const bf16x8*)&As[wm + f * 16 + (l & 15)][(l >> 4) << 3];
      bfr[f] = *(const bf16x8*)&Bs[wn + f * 16 + (l & 15)][(l >> 4) << 3];
    }
#pragma unroll
    for (int fm = 0; fm < 4; ++fm)
#pragma unroll
      for (int fn = 0; fn < 4; ++fn)
        acc[fm][fn] = __builtin_amdgcn_mfma_f32_16x16x32_bf16(
            af[fm], bfr[fn], acc[fm][fn], 0, 0, 0);
    __syncthreads();
  }
#pragma unroll
  for (int fm = 0; fm < 4; ++fm) {
    const int rbase = row0 + wm + fm * 16 + ((l >> 4) << 2);
#pragma unroll
    for (int fn = 0; fn < 4; ++fn) {
      const int col = col0 + wn + fn * 16 + (l & 15);
      const float bv = bias[col];
      const f32x4 v = acc[fm][fn];
#pragma unroll
      for (int j = 0; j < 4; ++j)
        out[(size_t)(rbase + j) * 512 + col] =
            __bfloat16_as_ushort(__float2bfloat16(v[j] + bv));
    }
  }
}

// -------- MFMA GEMM 2 --------
__global__ __launch_bounds__(256) void mfma_logits(
    const unsigned short* __restrict__ Zb,
    float* __restrict__ theta, float* __restrict__ Aout) {
  __shared__ unsigned short As[128][32];
  __shared__ unsigned short Bs[128][32];
  const int bz = blockIdx.z;
  const int b = bz >> 1, w = bz & 1;
  const unsigned short* X = Zb + (size_t)(w ? 2 : 0) * (6144 * 512) + (size_t)b * (768 * 512);
  const unsigned short* Y = Zb + (size_t)(w ? 3 : 1) * (6144 * 512) + (size_t)b * (768 * 512);
  float* out = (w ? Aout : theta) + (size_t)b * L2E;
  const int row0 = blockIdx.y * 128, col0 = blockIdx.x * 128;
  const int t = threadIdx.x, wv = t >> 6, l = t & 63;
  const int wm = (wv >> 1) * 64, wn = (wv & 1) * 64;

  f32x4 acc[4][4] = {};
  for (int k0 = 0; k0 < 512; k0 += 32) {
#pragma unroll
    for (int c = t; c < 512; c += 256) {
      const int rowi = c >> 2, seg = (c & 3) << 3;
      *(u16x8*)&As[rowi][seg] = *(const u16x8*)&X[(size_t)(row0 + rowi) * 512 + k0 + seg];
      *(u16x8*)&Bs[rowi][seg] = *(const u16x8*)&Y[(size_t)(col0 + rowi) * 512 + k0 + seg];
    }
    __syncthreads();
    bf16x8 af[4], bfr[4];
#pragma unroll
    for (int f = 0; f < 4; ++f) {
      af[f]  = *(const bf16x8*)&As[wm + f * 16 + (l & 15)][(l >> 4) << 3];
      bfr[f] = *(const bf16x8*)&Bs[wn + f * 16 + (l & 15)][(l >> 4) << 3];
    }
#pragma unroll
    for (int fm = 0; fm < 4; ++fm)
#pragma unroll
      for (int fn = 0; fn < 4; ++fn)
        acc[fm][fn] = __builtin_amdgcn_mfma_f32_16x16x32_bf16(
            af[fm], bfr[fn], acc[fm][fn], 0, 0, 0);
    __syncthreads();
  }
#pragma unroll
  for (int fm = 0; fm < 4; ++fm) {
    const int rbase = row0 + wm + fm * 16 + ((l >> 4) << 2);
#pragma unroll
    for (int fn = 0; fn < 4; ++fn) {
      const int col = col0 + wn + fn * 16 + (l & 15);
      const f32x4 v = acc[fm][fn];
#pragma unroll
      for (int j = 0; j < 4; ++j)
        out[(size_t)(rbase + j) * LL + col] = w ? logsigmoid_f(v[j]) : softplus_f(v[j]);
    }
  }
}

// -------- row-major theta,A -> packed bf16x2 compact-aligned diag --------
__global__ __launch_bounds__(256) void row2diag(
    const float* __restrict__ theta, const float* __restrict__ A,
    unsigned* __restrict__ TAc) {
  __shared__ float tT[64 * 66];
  __shared__ float tA[64 * 66];
  const int b = blockIdx.z;
  const float* inT = theta + (size_t)b * L2E;
  const float* inA = A + (size_t)b * L2E;
  unsigned* out = TAc + (size_t)b * LDIAG;
  const int r0 = blockIdx.y * 64, c0 = blockIdx.x * 64;
  const int t = threadIdx.x, lane = t & 63, grp = t >> 6;
  for (int it = 0; it < 16; ++it) {
    const int rr = it * 4 + grp;
    tT[rr * 66 + lane] = inT[(size_t)(r0 + rr) * LL + c0 + lane];
    tA[rr * 66 + lane] = inA[(size_t)(r0 + rr) * LL + c0 + lane];
  }
  __syncthreads();
  for (int si = grp; si < 127; si += 4) {
    const int s = r0 + c0 + si;
    const int rlo = max(r0, s - c0 - 63);
    const int rhi = min(r0 + 63, s - c0);
    const int base = Dmap(s) - lofs(s);
    const int r = rlo + lane;
    if (r <= rhi) {
      const int ii = (r - r0) * 66 + (s - r - c0);
      const unsigned ut = __bfloat16_as_ushort(__float2bfloat16(tT[ii]));
      const unsigned ua = __bfloat16_as_ushort(__float2bfloat16(tA[ii]));
      out[base + r] = (ua << 16) | ut;
    }
  }
}

// -------- compact-aligned bf16 E -> row-major fp32 (aln) --------
__global__ __launch_bounds__(256) void diag2row(
    const unsigned short* __restrict__ Edc, float* __restrict__ aln) {
  __shared__ float tile[64 * 66];
  const int b = blockIdx.z;
  const int r0 = blockIdx.y * 64;
  const int c0 = blockIdx.x * 64;
  const unsigned short* E = Edc + (size_t)b * LDIAG;
  float* out = aln + (size_t)b * L2E;
  const int t = threadIdx.x;
  const int lane = t & 63;
  const int grp = t >> 6;
  for (int si = grp; si < 127; si += 4) {
    const int s = r0 + c0 + si;
    const int rlo = max(r0, s - c0 - 63);
    const int rhi = min(r0 + 63, s - c0);
    const int base = Dmap(s) - lofs(s);
    const int r = rlo + lane;
    if (r <= rhi) {
      tile[(r - r0) * 66 + (s - r - c0)] =
          __uint_as_float(((unsigned)E[base + r]) << 16);
    }
  }
  __syncthreads();
  for (int it = 0; it < 16; ++it) {
    const int rr = it * 4 + grp;
    out[(size_t)(r0 + rr) * LL + c0 + lane] = tile[rr * 66 + lane];
  }
}

__device__ __forceinline__ void lds_release_store(int* p, int v) {
  asm volatile("s_waitcnt lgkmcnt(0)" ::: "memory");
  __hip_atomic_store(p, v, __ATOMIC_RELAXED, __HIP_MEMORY_SCOPE_WORKGROUP);
}

// -------- NW forward: 2 batches/block (6 waves/CU), named-register slots ----
__global__ __launch_bounds__(384, 1) void nw_fwd(
    const unsigned* __restrict__ TAc, float* __restrict__ Vr) {
  __shared__ int Pf[2][4];
  __shared__ float BvF[2][2][1024];

  const int bi = threadIdx.x / 192;
  const int tl = threadIdx.x - bi * 192;
  const int b = blockIdx.x * 2 + bi;
  const unsigned* TA = TAc + (size_t)b * LDIAG;
  float* V = Vr + (size_t)b * (1536 * LL);

  const int w = tl >> 6, l = tl & 63;
  const int rowb = 4 * tl;
  const int kb = 256 * w + 2;

  if (tl < 4) Pf[bi][tl] = 0;
  __syncthreads();

  uint4 q0, q1, q2, q3;
  {
    int s0;
    s0 = kb - 2; q2 = *(const uint4*)(TA + (Dmap(s0) + rowb - lofs(s0)));
    s0 = kb - 1; q3 = *(const uint4*)(TA + (Dmap(s0) + rowb - lofs(s0)));
    s0 = kb;     q0 = *(const uint4*)(TA + (Dmap(s0) + rowb - lofs(s0)));
    s0 = kb + 1; q1 = *(const uint4*)(TA + (Dmap(s0) + rowb - lofs(s0)));
  }
  int sL = kb + 2;
  int iL = Dmap(sL) + rowb - lofs(sL);
  int iS4 = (kb - 2) * LL + rowb;
  float4 p1 = make_float4(NEGF, NEGF, NEGF, NEGF);
  float4 p2 = p1;
  float rvh = NEGF;
  float pv3 = NEGF;

#define FSTEP(U, Q) { \
  const int k = kg + (U); \
  float rv = __shfl_up(pv3, 1); \
  if (l == 0) rv = (w == 0) ? NEGF : BvF[bi][w - 1][min(k - kb + 255, 1023)]; \
  float rdg = rvh; \
  if (l == 0 && w == 0) rdg = (k == 2) ? 0.f : NEGF; \
  const int d = k - rowb - 2; \
  float4 vv; \
  { const float av = bf_hi(Q.x), tv = bf_lo(Q.x); \
    const float lft = av + p1.x, up = av + rv; \
    const float mx = fmaxf(rdg, fmaxf(lft, up)); \
    const float val = tv + mx + __logf(__expf(rdg - mx) + __expf(lft - mx) + __expf(up - mx)); \
    vv.x = ((unsigned)d <= 767u) ? val : NEGF; } \
  { const float av = bf_hi(Q.y), tv = bf_lo(Q.y); \
    const float lft = av + p1.y, up = av + p1.x; \
    const float mx = fmaxf(p2.x, fmaxf(lft, up)); \
    const float val = tv + mx + __logf(__expf(p2.x - mx) + __expf(lft - mx) + __expf(up - mx)); \
    vv.y = ((unsigned)(d - 1) <= 767u) ? val : NEGF; } \
  { const float av = bf_hi(Q.z), tv = bf_lo(Q.z); \
    const float lft = av + p1.z, up = av + p1.y; \
    const float mx = fmaxf(p2.y, fmaxf(lft, up)); \
    const float val = tv + mx + __logf(__expf(p2.y - mx) + __expf(lft - mx) + __expf(up - mx)); \
    vv.z = ((unsigned)(d - 2) <= 767u) ? val : NEGF; } \
  { const float av = bf_hi(Q.w), tv = bf_lo(Q.w); \
    const float lft = av + p1.w, up = av + p1.z; \
    const float mx = fmaxf(p2.z, fmaxf(lft, up)); \
    const float val = tv + mx + __logf(__expf(p2.z - mx) + __expf(lft - mx) + __expf(up - mx)); \
    vv.w = ((unsigned)(d - 3) <= 767u) ? val : NEGF; } \
  Q = *(const uint4*)(TA + iL); \
  iL += dIa(sL); ++sL; \
  *(float4*)(V + iS4) = vv; \
  iS4 += LL; \
  if (l == 63 && w < 2) BvF[bi][w][k - kb] = vv.w; \
  pv3 = vv.w; \
  rvh = rv; \
  p2 = p1; p1 = vv; \
}

  for (int kg = kb; kg < kb + 1024; kg += 8) {
    if (l == 0 && w > 0 && kg < kb + 768) {
      const int need = min(kg + 6, kb + 766);
      while (__hip_atomic_load(&Pf[bi][w - 1], __ATOMIC_ACQUIRE,
                               __HIP_MEMORY_SCOPE_WORKGROUP) < need) {}
    }
    FSTEP(0, q2) FSTEP(1, q3) FSTEP(2, q0) FSTEP(3, q1)
    FSTEP(4, q2) FSTEP(5, q3) FSTEP(6, q0) FSTEP(7, q1)
    if (l == 63 && w < 2) lds_release_store(&Pf[bi][w], kg + 7);
  }
#undef FSTEP
}

// -------- NW backward: 2 batches/block (6 waves/CU), named-register slots ---
__global__ __launch_bounds__(384, 1) void nw_bwd(
    const unsigned* __restrict__ TAc, const float* __restrict__ Vr,
    unsigned short* __restrict__ Edc) {
  __shared__ int Pb[2][4];
  __shared__ float Bv2[2][2][1024];
  __shared__ float Be2[2][2][1024];

  const int bi = threadIdx.x / 192;
  const int tl = threadIdx.x - bi * 192;
  const int b = blockIdx.x * 2 + bi;
  const unsigned* TA = TAc + (size_t)b * LDIAG;
  const float* V = Vr + (size_t)b * (1536 * LL);
  unsigned short* Eo = Edc + (size_t)b * LDIAG;

  const int w = tl >> 6, l = tl & 63;
  const int rowb = 4 * tl;
  const int kb = 256 * w + 2;
  const int ke = kb + 1023;

  if (tl < 4) Pb[bi][tl] = 0x7fffffff;
  __syncthreads();

  float4 V0, V1, V2, V3;
  uint4 K0, K1, K2, K3;
  unsigned F0, F1, F2, F3;
  {
    int sv, sk, ik;
    sv = ke - 2; V1 = *(const float4*)(V + (sv * LL + rowb));
    sk = ke - 1; ik = Dmap(sk) + rowb - lofs(sk);
    K1 = *(const uint4*)(TA + ik); F1 = TA[ik + 4];
    sv = ke - 3; V0 = *(const float4*)(V + (sv * LL + rowb));
    sk = ke - 2; ik = Dmap(sk) + rowb - lofs(sk);
    K0 = *(const uint4*)(TA + ik); F0 = TA[ik + 4];
    sv = ke - 4; V3 = *(const float4*)(V + (sv * LL + rowb));
    sk = ke - 3; ik = Dmap(sk) + rowb - lofs(sk);
    K3 = *(const uint4*)(TA + ik); F3 = TA[ik + 4];
    sv = ke - 5; V2 = *(const float4*)(V + (sv * LL + rowb));
    sk = ke - 4; ik = Dmap(sk) + rowb - lofs(sk);
    K2 = *(const uint4*)(TA + ik); F2 = TA[ik + 4];
  }
  int iV = (ke - 6) * LL + rowb;
  int sK1s = ke - 5;
  int iK1 = Dmap(sK1s) + rowb - lofs(sK1s);
  float4 T0, T1;
  {
    const int j0 = Dmap(ke) + rowb - lofs(ke);
    T0 = make_float4(bf_lo(TA[j0 + 1]), bf_lo(TA[j0 + 2]),
                     bf_lo(TA[j0 + 3]), bf_lo(TA[j0 + 4]));
    T1 = make_float4(0.f, 0.f, 0.f, 0.f);
  }
  int sE = ke - 2;
  int iE = Dmap(sE) + rowb - lofs(sE);
  float4 n1v = {}, n1e = {}, n2v = {}, n2e = {}, hv = {}, he = {};
  float pv0 = 0.f, pe0 = 0.f;

#define BCELL(VCr, DO, ILT, N2Vr, N2Er, TKr, S1a, S1b, N1Vr, N1Er, HVr, HEr, OUT) { \
  const bool ok  = (unsigned)(d - (DO)) <= 767u; \
  const bool jlt = (d - (DO)) < 767; \
  float acc = 0.f; \
  if ((ILT) && jlt) acc += N2Er * __expf(VCr - N2Vr + TKr); \
  if (jlt)          acc += HEr * __expf(bf_hi(S1a) + VCr - HVr + bf_lo(S1a)); \
  if ((ILT))        acc += N1Er * __expf(bf_hi(S1b) + VCr - N1Vr + bf_lo(S1b)); \
  OUT = ok ? acc : 0.f; }

#define BSTEP(U, SV, SK, SF, TRD, TWR) { \
  const int k = kg - (U); \
  { float nv3 = __shfl_down(pv0, 1); \
    float ne3 = __shfl_down(pe0, 1); \
    if (l == 63) { \
      if (w < 2) { const int bi2 = min(ke - k + 255, 1023); nv3 = Bv2[bi][w][bi2]; ne3 = Be2[bi][w][bi2]; } \
      else { nv3 = 0.f; ne3 = 0.f; } } \
    n1v.w = nv3; n1e.w = ne3; } \
  const int d = k - rowb - 2; \
  unsigned fifth = __shfl_down(SK.x, 1); \
  if (l == 63) fifth = SF; \
  const float4 vc = SV; \
  float4 ev; \
  BCELL(vc.x, 0, true, n2v.x, n2e.x, TRD.x, SK.x, SK.y, n1v.x, n1e.x, hv.x, he.x, ev.x) \
  BCELL(vc.y, 1, true, n2v.y, n2e.y, TRD.y, SK.y, SK.z, n1v.y, n1e.y, hv.y, he.y, ev.y) \
  BCELL(vc.z, 2, true, n2v.z, n2e.z, TRD.z, SK.z, SK.w, n1v.z, n1e.z, hv.z, he.z, ev.z) \
  BCELL(vc.w, 3, (tl != 191), n2v.w, n2e.w, TRD.w, SK.w, fifth, n1v.w, n1e.w, hv.w, he.w, ev.w) \
  if (k == 2 * LL && tl == 191) ev.w = 1.f; \
  TWR.x = bf_lo(SK.y); TWR.y = bf_lo(SK.z); TWR.z = bf_lo(SK.w); TWR.w = bf_lo(fifth); \
  SV = *(const float4*)(V + max(iV, 0)); \
  iV -= LL; \
  { const int ic = max(iK1, 0); \
    SK = *(const uint4*)(TA + ic); \
    if (l == 63) SF = TA[ic + 4]; \
    iK1 -= dIa(sK1s - 1); --sK1s; } \
  if ((unsigned)d <= 770u) { \
    ushort4 st; \
    st.x = __bfloat16_as_ushort(__float2bfloat16(ev.x)); \
    st.y = __bfloat16_as_ushort(__float2bfloat16(ev.y)); \
    st.z = __bfloat16_as_ushort(__float2bfloat16(ev.z)); \
    st.w = __bfloat16_as_ushort(__float2bfloat16(ev.w)); \
    *(ushort4*)(Eo + iE) = st; } \
  iE -= dIa(sE - 1); --sE; \
  if (l == 0 && w > 0) { Bv2[bi][w - 1][ke - k] = vc.x; Be2[bi][w - 1][ke - k] = ev.x; } \
  pv0 = vc.x; pe0 = ev.x; \
  n2v = n1v; n2e = n1e; \
  n1v.x = vc.y; n1v.y = vc.z; n1v.z = vc.w; \
  n1e.x = ev.y; n1e.y = ev.z; n1e.z = ev.w; \
  hv = vc; he = ev; \
}

  for (int kg = ke; kg > ke - 1024; kg -= 8) {
    if (l == 63 && w < 2 && kg >= kb + 255) {
      const int need = max(kg - 6, kb + 256);
      while (__hip_atomic_load(&Pb[bi][w + 1], __ATOMIC_ACQUIRE,
                               __HIP_MEMORY_SCOPE_WORKGROUP) > need) {}
    }
    BSTEP(0, V1, K1, F1, T0, T1) BSTEP(1, V0, K0, F0, T1, T0)
    BSTEP(2, V3, K3, F3, T0, T1) BSTEP(3, V2, K2, F2, T1, T0)
    BSTEP(4, V1, K1, F1, T0, T1) BSTEP(5, V0, K0, F0, T1, T0)
    BSTEP(6, V3, K3, F3, T0, T1) BSTEP(7, V2, K2, F2, T1, T0)
    if (l == 0 && w > 0) lds_release_store(&Pb[bi][w], kg - 7);
  }
#undef BSTEP
#undef BCELL
}

}  // namespace

extern "C" void kernel_launch(void* const* d_in, const int* in_sizes, int n_in,
                              void* d_out, int out_size, void* d_ws, size_t ws_size,
                              hipStream_t stream) {
  const float* hx = (const float*)d_in[0];
  const float* hy = (const float*)d_in[1];
  const float* Wm = (const float*)d_in[2];
  const float* bm = (const float*)d_in[3];
  const float* Wg = (const float*)d_in[4];
  const float* bg = (const float*)d_in[5];

  float* aln   = (float*)d_out;
  float* theta = aln + (size_t)BB * L2E;
  float* A     = theta + (size_t)BB * L2E;

  unsigned short* hxb = (unsigned short*)d_ws;
  unsigned short* hyb = hxb + (size_t)6144 * 512;
  unsigned short* Wmb = hyb + (size_t)6144 * 512;
  unsigned short* Wgb = Wmb + (size_t)512 * 512;
  unsigned short* Zb  = Wgb + (size_t)512 * 512;
  unsigned* TAc = (unsigned*)d_ws;
  float* Vr = (float*)d_ws + (size_t)BB * LDIAG;
  unsigned short* Edc = (unsigned short*)(Vr + (size_t)BB * (1536 * LL));

  const int nX = 6144 * 512, nW = 512 * 512;
  tobf16<<<(nX / 4 + 255) / 256, 256, 0, stream>>>(hx, hxb, nX);
  tobf16<<<(nX / 4 + 255) / 256, 256, 0, stream>>>(hy, hyb, nX);
  tobf16<<<(nW / 4 + 255) / 256, 256, 0, stream>>>(Wm, Wmb, nW);
  tobf16<<<(nW / 4 + 255) / 256, 256, 0, stream>>>(Wg, Wgb, nW);

  mfma_linear<<<dim3(4, 48, 4), 256, 0, stream>>>(hxb, Wmb, bm, bg, Zb);
  mfma_logits<<<dim3(6, 6, 16), 256, 0, stream>>>(Zb, theta, A);

  row2diag<<<dim3(LL / 64, LL / 64, BB), 256, 0, stream>>>(theta, A, TAc);
  nw_fwd<<<dim3(BB / 2), 384, 0, stream>>>(TAc, Vr);
  nw_bwd<<<dim3(BB / 2), 384, 0, stream>>>(TAc, Vr, Edc);
  diag2row<<<dim3(LL / 64, LL / 64, BB), 256, 0, stream>>>(Edc, aln);
}

// Round 16
// 1657.271 us; speedup vs baseline: 1.4376x; 1.1958x over previous
//
#include <hip/hip_runtime.h>
#include <hip/hip_bf16.h>
#include <math.h>

namespace {

constexpr int BB = 8;
constexpr int LL = 768;
constexpr int DD = 512;
constexpr int L2E = LL * LL;
constexpr int LDIAG = L2E + 8192;
constexpr float NEGF = -1e9f;

typedef __attribute__((ext_vector_type(8))) short bf16x8;
typedef __attribute__((ext_vector_type(8))) unsigned short u16x8;
typedef __attribute__((ext_vector_type(4))) float f32x4;

__device__ __forceinline__ float softplus_f(float x) {
  return x > 0.f ? x + log1pf(expf(-x)) : log1pf(expf(x));
}
__device__ __forceinline__ float logsigmoid_f(float x) {
  return x > 0.f ? -log1pf(expf(-x)) : x - log1pf(expf(x));
}

__device__ __forceinline__ float bf_lo(unsigned u) { return __uint_as_float(u << 16); }
__device__ __forceinline__ float bf_hi(unsigned u) { return __uint_as_float(u & 0xffff0000u); }

__device__ __forceinline__ int lofs(int s) { return (s > LL - 1) ? (s - (LL - 1)) : 0; }

__device__ __forceinline__ int Dmap(int s) {
  if (s <= LL - 1) {
    const int m = s >> 2, i = s & 3;
    const int c = (i == 0) ? 4 : (i == 1) ? 8 : (i == 2) ? 16 : 24;
    return 8 * m * m + (20 + 4 * i) * m + c;
  }
  const int q = (s - LL) >> 2, i = (s - LL) & 3;
  const int base = 298757 + 3092 * q - 8 * q * q;
  const int off = (i == 0) ? 0 : (i == 1) ? (773 - 4 * q)
                : (i == 2) ? (1546 - 8 * q) : (2315 - 12 * q);
  return base + off;
}
__device__ __forceinline__ int dDa(int s) {
  if (s < LL - 1) return s + 4 + ((-s) & 3);
  if (s == LL - 1) return 773;
  return 1539 - s + ((s + 2) & 3);
}
__device__ __forceinline__ int dIa(int s) { return dDa(s) - ((s >= LL - 1) ? 1 : 0); }

// -------- fp32 -> bf16 convert --------
__global__ __launch_bounds__(256) void tobf16(
    const float* __restrict__ src, unsigned short* __restrict__ dst, int n) {
  const int i = (blockIdx.x * 256 + threadIdx.x) * 4;
  if (i < n) {
    const float4 v = *(const float4*)(src + i);
    ushort4 o;
    o.x = __bfloat16_as_ushort(__float2bfloat16(v.x));
    o.y = __bfloat16_as_ushort(__float2bfloat16(v.y));
    o.z = __bfloat16_as_ushort(__float2bfloat16(v.z));
    o.w = __bfloat16_as_ushort(__float2bfloat16(v.w));
    *(ushort4*)(dst + i) = o;
  }
}

// -------- MFMA GEMM 1 --------
__global__ __launch_bounds__(256) void mfma_linear(
    const unsigned short* __restrict__ Xb, const unsigned short* __restrict__ Wb,
    const float* __restrict__ bm, const float* __restrict__ bg,
    unsigned short* __restrict__ Zb) {
  __shared__ unsigned short As[128][32];
  __shared__ unsigned short Bs[128][32];
  const int which = blockIdx.z;
  const unsigned short* X = Xb + (size_t)(which & 1) * (6144 * 512);
  const unsigned short* W = Wb + (size_t)(which >> 1) * (512 * 512);
  const float* bias = (which >= 2) ? bg : bm;
  unsigned short* out = Zb + (size_t)which * (6144 * 512);
  const int row0 = blockIdx.y * 128, col0 = blockIdx.x * 128;
  const int t = threadIdx.x, wv = t >> 6, l = t & 63;
  const int wm = (wv >> 1) * 64, wn = (wv & 1) * 64;

  f32x4 acc[4][4] = {};
  for (int k0 = 0; k0 < 512; k0 += 32) {
#pragma unroll
    for (int c = t; c < 512; c += 256) {
      const int rowi = c >> 2, seg = (c & 3) << 3;
      *(u16x8*)&As[rowi][seg] = *(const u16x8*)&X[(size_t)(row0 + rowi) * 512 + k0 + seg];
      *(u16x8*)&Bs[rowi][seg] = *(const u16x8*)&W[(size_t)(col0 + rowi) * 512 + k0 + seg];
    }
    __syncthreads();
    bf16x8 af[4], bfr[4];
#pragma unroll
    for (int f = 0; f < 4; ++f) {
      af[f]  = *(const bf16x8*)&As[wm + f * 16 + (l & 15)][(l >> 4) << 3];
      bfr[f] = *(const bf16x8*)&Bs[wn + f * 16 + (l & 15)][(l >> 4) << 3];
    }
#pragma unroll
    for (int fm = 0; fm < 4; ++fm)
#pragma unroll
      for (int fn = 0; fn < 4; ++fn)
        acc[fm][fn] = __builtin_amdgcn_mfma_f32_16x16x32_bf16(
            af[fm], bfr[fn], acc[fm][fn], 0, 0, 0);
    __syncthreads();
  }
#pragma unroll
  for (int fm = 0; fm < 4; ++fm) {
    const int rbase = row0 + wm + fm * 16 + ((l >> 4) << 2);
#pragma unroll
    for (int fn = 0; fn < 4; ++fn) {
      const int col = col0 + wn + fn * 16 + (l & 15);
      const float bv = bias[col];
      const f32x4 v = acc[fm][fn];
#pragma unroll
      for (int j = 0; j < 4; ++j)
        out[(size_t)(rbase + j) * 512 + col] =
            __bfloat16_as_ushort(__float2bfloat16(v[j] + bv));
    }
  }
}

// -------- MFMA GEMM 2 --------
__global__ __launch_bounds__(256) void mfma_logits(
    const unsigned short* __restrict__ Zb,
    float* __restrict__ theta, float* __restrict__ Aout) {
  __shared__ unsigned short As[128][32];
  __shared__ unsigned short Bs[128][32];
  const int bz = blockIdx.z;
  const int b = bz >> 1, w = bz & 1;
  const unsigned short* X = Zb + (size_t)(w ? 2 : 0) * (6144 * 512) + (size_t)b * (768 * 512);
  const unsigned short* Y = Zb + (size_t)(w ? 3 : 1) * (6144 * 512) + (size_t)b * (768 * 512);
  float* out = (w ? Aout : theta) + (size_t)b * L2E;
  const int row0 = blockIdx.y * 128, col0 = blockIdx.x * 128;
  const int t = threadIdx.x, wv = t >> 6, l = t & 63;
  const int wm = (wv >> 1) * 64, wn = (wv & 1) * 64;

  f32x4 acc[4][4] = {};
  for (int k0 = 0; k0 < 512; k0 += 32) {
#pragma unroll
    for (int c = t; c < 512; c += 256) {
      const int rowi = c >> 2, seg = (c & 3) << 3;
      *(u16x8*)&As[rowi][seg] = *(const u16x8*)&X[(size_t)(row0 + rowi) * 512 + k0 + seg];
      *(u16x8*)&Bs[rowi][seg] = *(const u16x8*)&Y[(size_t)(col0 + rowi) * 512 + k0 + seg];
    }
    __syncthreads();
    bf16x8 af[4], bfr[4];
#pragma unroll
    for (int f = 0; f < 4; ++f) {
      af[f]  = *(const bf16x8*)&As[wm + f * 16 + (l & 15)][(l >> 4) << 3];
      bfr[f] = *(const bf16x8*)&Bs[wn + f * 16 + (l & 15)][(l >> 4) << 3];
    }
#pragma unroll
    for (int fm = 0; fm < 4; ++fm)
#pragma unroll
      for (int fn = 0; fn < 4; ++fn)
        acc[fm][fn] = __builtin_amdgcn_mfma_f32_16x16x32_bf16(
            af[fm], bfr[fn], acc[fm][fn], 0, 0, 0);
    __syncthreads();
  }
#pragma unroll
  for (int fm = 0; fm < 4; ++fm) {
    const int rbase = row0 + wm + fm * 16 + ((l >> 4) << 2);
#pragma unroll
    for (int fn = 0; fn < 4; ++fn) {
      const int col = col0 + wn + fn * 16 + (l & 15);
      const f32x4 v = acc[fm][fn];
#pragma unroll
      for (int j = 0; j < 4; ++j)
        out[(size_t)(rbase + j) * LL + col] = w ? logsigmoid_f(v[j]) : softplus_f(v[j]);
    }
  }
}

// -------- row-major theta,A -> packed bf16x2 compact-aligned diag --------
__global__ __launch_bounds__(256) void row2diag(
    const float* __restrict__ theta, const float* __restrict__ A,
    unsigned* __restrict__ TAc) {
  __shared__ float tT[64 * 66];
  __shared__ float tA[64 * 66];
  const int b = blockIdx.z;
  const float* inT = theta + (size_t)b * L2E;
  const float* inA = A + (size_t)b * L2E;
  unsigned* out = TAc + (size_t)b * LDIAG;
  const int r0 = blockIdx.y * 64, c0 = blockIdx.x * 64;
  const int t = threadIdx.x, lane = t & 63, grp = t >> 6;
  for (int it = 0; it < 16; ++it) {
    const int rr = it * 4 + grp;
    tT[rr * 66 + lane] = inT[(size_t)(r0 + rr) * LL + c0 + lane];
    tA[rr * 66 + lane] = inA[(size_t)(r0 + rr) * LL + c0 + lane];
  }
  __syncthreads();
  for (int si = grp; si < 127; si += 4) {
    const int s = r0 + c0 + si;
    const int rlo = max(r0, s - c0 - 63);
    const int rhi = min(r0 + 63, s - c0);
    const int base = Dmap(s) - lofs(s);
    const int r = rlo + lane;
    if (r <= rhi) {
      const int ii = (r - r0) * 66 + (s - r - c0);
      const unsigned ut = __bfloat16_as_ushort(__float2bfloat16(tT[ii]));
      const unsigned ua = __bfloat16_as_ushort(__float2bfloat16(tA[ii]));
      out[base + r] = (ua << 16) | ut;
    }
  }
}

// -------- compact-aligned bf16 E -> row-major fp32 (aln) --------
__global__ __launch_bounds__(256) void diag2row(
    const unsigned short* __restrict__ Edc, float* __restrict__ aln) {
  __shared__ float tile[64 * 66];
  const int b = blockIdx.z;
  const int r0 = blockIdx.y * 64;
  const int c0 = blockIdx.x * 64;
  const unsigned short* E = Edc + (size_t)b * LDIAG;
  float* out = aln + (size_t)b * L2E;
  const int t = threadIdx.x;
  const int lane = t & 63;
  const int grp = t >> 6;
  for (int si = grp; si < 127; si += 4) {
    const int s = r0 + c0 + si;
    const int rlo = max(r0, s - c0 - 63);
    const int rhi = min(r0 + 63, s - c0);
    const int base = Dmap(s) - lofs(s);
    const int r = rlo + lane;
    if (r <= rhi) {
      tile[(r - r0) * 66 + (s - r - c0)] =
          __uint_as_float(((unsigned)E[base + r]) << 16);
    }
  }
  __syncthreads();
  for (int it = 0; it < 16; ++it) {
    const int rr = it * 4 + grp;
    out[(size_t)(r0 + rr) * LL + c0 + lane] = tile[rr * 66 + lane];
  }
}

__device__ __forceinline__ void lds_release_store(int* p, int v) {
  asm volatile("s_waitcnt lgkmcnt(0)" ::: "memory");
  __hip_atomic_store(p, v, __ATOMIC_RELAXED, __HIP_MEMORY_SCOPE_WORKGROUP);
}

// -------- Fused NW fwd+bwd: 1 batch/block (R13 engine), V stays XCD-local ---
__global__ __launch_bounds__(192, 1) void nw_fused(
    const unsigned* __restrict__ TAc, float* __restrict__ Vr,
    unsigned short* __restrict__ Edc) {
  __shared__ int Pf[4], Pb[4];
  __shared__ float BvF[2][1024];
  __shared__ float Bv2[2][1024];
  __shared__ float Be2[2][1024];

  const int b = blockIdx.x;
  const unsigned* TA = TAc + (size_t)b * LDIAG;
  float* V = Vr + (size_t)b * (1536 * LL);
  unsigned short* Eo = Edc + (size_t)b * LDIAG;

  const int t = threadIdx.x;
  const int w = t >> 6, l = t & 63;
  const int rowb = 4 * t;
  const int kb = 256 * w + 2;
  const int ke = kb + 1023;

  if (t < 4) { Pf[t] = 0; Pb[t] = 0x7fffffff; }
  __syncthreads();

  // ================= forward =================
  {
    uint4 q0, q1, q2, q3;
    {
      int s0;
      s0 = kb - 2; q2 = *(const uint4*)(TA + (Dmap(s0) + rowb - lofs(s0)));
      s0 = kb - 1; q3 = *(const uint4*)(TA + (Dmap(s0) + rowb - lofs(s0)));
      s0 = kb;     q0 = *(const uint4*)(TA + (Dmap(s0) + rowb - lofs(s0)));
      s0 = kb + 1; q1 = *(const uint4*)(TA + (Dmap(s0) + rowb - lofs(s0)));
    }
    int sL = kb + 2;
    int iL = Dmap(sL) + rowb - lofs(sL);
    int iS4 = (kb - 2) * LL + rowb;
    float4 p1 = make_float4(NEGF, NEGF, NEGF, NEGF);
    float4 p2 = p1;
    float rvh = NEGF;
    float pv3 = NEGF;

#define FSTEP(U, Q) { \
  const int k = kg + (U); \
  float rv = __shfl_up(pv3, 1); \
  if (l == 0) rv = (w == 0) ? NEGF : BvF[w - 1][min(k - kb + 255, 1023)]; \
  float rdg = rvh; \
  if (l == 0 && w == 0) rdg = (k == 2) ? 0.f : NEGF; \
  const int d = k - rowb - 2; \
  float4 vv; \
  { const float av = bf_hi(Q.x), tv = bf_lo(Q.x); \
    const float lft = av + p1.x, up = av + rv; \
    const float mx = fmaxf(rdg, fmaxf(lft, up)); \
    const float val = tv + mx + __logf(__expf(rdg - mx) + __expf(lft - mx) + __expf(up - mx)); \
    vv.x = ((unsigned)d <= 767u) ? val : NEGF; } \
  { const float av = bf_hi(Q.y), tv = bf_lo(Q.y); \
    const float lft = av + p1.y, up = av + p1.x; \
    const float mx = fmaxf(p2.x, fmaxf(lft, up)); \
    const float val = tv + mx + __logf(__expf(p2.x - mx) + __expf(lft - mx) + __expf(up - mx)); \
    vv.y = ((unsigned)(d - 1) <= 767u) ? val : NEGF; } \
  { const float av = bf_hi(Q.z), tv = bf_lo(Q.z); \
    const float lft = av + p1.z, up = av + p1.y; \
    const float mx = fmaxf(p2.y, fmaxf(lft, up)); \
    const float val = tv + mx + __logf(__expf(p2.y - mx) + __expf(lft - mx) + __expf(up - mx)); \
    vv.z = ((unsigned)(d - 2) <= 767u) ? val : NEGF; } \
  { const float av = bf_hi(Q.w), tv = bf_lo(Q.w); \
    const float lft = av + p1.w, up = av + p1.z; \
    const float mx = fmaxf(p2.z, fmaxf(lft, up)); \
    const float val = tv + mx + __logf(__expf(p2.z - mx) + __expf(lft - mx) + __expf(up - mx)); \
    vv.w = ((unsigned)(d - 3) <= 767u) ? val : NEGF; } \
  Q = *(const uint4*)(TA + iL); \
  iL += dIa(sL); ++sL; \
  *(float4*)(V + iS4) = vv; \
  iS4 += LL; \
  if (l == 63 && w < 2) BvF[w][k - kb] = vv.w; \
  pv3 = vv.w; \
  rvh = rv; \
  p2 = p1; p1 = vv; \
}

    for (int kg = kb; kg < kb + 1024; kg += 8) {
      if (l == 0 && w > 0 && kg < kb + 768) {
        const int need = min(kg + 6, kb + 766);
        while (__hip_atomic_load(&Pf[w - 1], __ATOMIC_ACQUIRE,
                                 __HIP_MEMORY_SCOPE_WORKGROUP) < need) {}
      }
      FSTEP(0, q2) FSTEP(1, q3) FSTEP(2, q0) FSTEP(3, q1)
      FSTEP(4, q2) FSTEP(5, q3) FSTEP(6, q0) FSTEP(7, q1)
      if (l == 63 && w < 2) lds_release_store(&Pf[w], kg + 7);
    }
#undef FSTEP
  }
  __syncthreads();  // drains vmcnt: all V stores visible to block (same XCD L2)

  // ================= backward =================
  {
    float4 V0, V1, V2, V3;
    uint4 K0, K1, K2, K3;
    unsigned F0, F1, F2, F3;
    {
      int sv, sk, ik;
      sv = ke - 2; V1 = *(const float4*)(V + (sv * LL + rowb));
      sk = ke - 1; ik = Dmap(sk) + rowb - lofs(sk);
      K1 = *(const uint4*)(TA + ik); F1 = TA[ik + 4];
      sv = ke - 3; V0 = *(const float4*)(V + (sv * LL + rowb));
      sk = ke - 2; ik = Dmap(sk) + rowb - lofs(sk);
      K0 = *(const uint4*)(TA + ik); F0 = TA[ik + 4];
      sv = ke - 4; V3 = *(const float4*)(V + (sv * LL + rowb));
      sk = ke - 3; ik = Dmap(sk) + rowb - lofs(sk);
      K3 = *(const uint4*)(TA + ik); F3 = TA[ik + 4];
      sv = ke - 5; V2 = *(const float4*)(V + (sv * LL + rowb));
      sk = ke - 4; ik = Dmap(sk) + rowb - lofs(sk);
      K2 = *(const uint4*)(TA + ik); F2 = TA[ik + 4];
    }
    int iV = (ke - 6) * LL + rowb;
    int sK1s = ke - 5;
    int iK1 = Dmap(sK1s) + rowb - lofs(sK1s);
    float4 T0, T1;
    {
      const int j0 = Dmap(ke) + rowb - lofs(ke);
      T0 = make_float4(bf_lo(TA[j0 + 1]), bf_lo(TA[j0 + 2]),
                       bf_lo(TA[j0 + 3]), bf_lo(TA[j0 + 4]));
      T1 = make_float4(0.f, 0.f, 0.f, 0.f);
    }
    int sE = ke - 2;
    int iE = Dmap(sE) + rowb - lofs(sE);
    float4 n1v = {}, n1e = {}, n2v = {}, n2e = {}, hv = {}, he = {};
    float pv0 = 0.f, pe0 = 0.f;

#define BCELL(VCr, DO, ILT, N2Vr, N2Er, TKr, S1a, S1b, N1Vr, N1Er, HVr, HEr, OUT) { \
  const bool ok  = (unsigned)(d - (DO)) <= 767u; \
  const bool jlt = (d - (DO)) < 767; \
  float acc = 0.f; \
  if ((ILT) && jlt) acc += N2Er * __expf(VCr - N2Vr + TKr); \
  if (jlt)          acc += HEr * __expf(bf_hi(S1a) + VCr - HVr + bf_lo(S1a)); \
  if ((ILT))        acc += N1Er * __expf(bf_hi(S1b) + VCr - N1Vr + bf_lo(S1b)); \
  OUT = ok ? acc : 0.f; }

#define BSTEP(U, SV, SK, SF, TRD, TWR) { \
  const int k = kg - (U); \
  { float nv3 = __shfl_down(pv0, 1); \
    float ne3 = __shfl_down(pe0, 1); \
    if (l == 63) { \
      if (w < 2) { const int bi2 = min(ke - k + 255, 1023); nv3 = Bv2[w][bi2]; ne3 = Be2[w][bi2]; } \
      else { nv3 = 0.f; ne3 = 0.f; } } \
    n1v.w = nv3; n1e.w = ne3; } \
  const int d = k - rowb - 2; \
  unsigned fifth = __shfl_down(SK.x, 1); \
  if (l == 63) fifth = SF; \
  const float4 vc = SV; \
  float4 ev; \
  BCELL(vc.x, 0, true, n2v.x, n2e.x, TRD.x, SK.x, SK.y, n1v.x, n1e.x, hv.x, he.x, ev.x) \
  BCELL(vc.y, 1, true, n2v.y, n2e.y, TRD.y, SK.y, SK.z, n1v.y, n1e.y, hv.y, he.y, ev.y) \
  BCELL(vc.z, 2, true, n2v.z, n2e.z, TRD.z, SK.z, SK.w, n1v.z, n1e.z, hv.z, he.z, ev.z) \
  BCELL(vc.w, 3, (t != 191), n2v.w, n2e.w, TRD.w, SK.w, fifth, n1v.w, n1e.w, hv.w, he.w, ev.w) \
  if (k == 2 * LL && t == 191) ev.w = 1.f; \
  TWR.x = bf_lo(SK.y); TWR.y = bf_lo(SK.z); TWR.z = bf_lo(SK.w); TWR.w = bf_lo(fifth); \
  SV = *(const float4*)(V + max(iV, 0)); \
  iV -= LL; \
  { const int ic = max(iK1, 0); \
    SK = *(const uint4*)(TA + ic); \
    if (l == 63) SF = TA[ic + 4]; \
    iK1 -= dIa(sK1s - 1); --sK1s; } \
  if ((unsigned)d <= 770u) { \
    ushort4 st; \
    st.x = __bfloat16_as_ushort(__float2bfloat16(ev.x)); \
    st.y = __bfloat16_as_ushort(__float2bfloat16(ev.y)); \
    st.z = __bfloat16_as_ushort(__float2bfloat16(ev.z)); \
    st.w = __bfloat16_as_ushort(__float2bfloat16(ev.w)); \
    *(ushort4*)(Eo + iE) = st; } \
  iE -= dIa(sE - 1); --sE; \
  if (l == 0 && w > 0) { Bv2[w - 1][ke - k] = vc.x; Be2[w - 1][ke - k] = ev.x; } \
  pv0 = vc.x; pe0 = ev.x; \
  n2v = n1v; n2e = n1e; \
  n1v.x = vc.y; n1v.y = vc.z; n1v.z = vc.w; \
  n1e.x = ev.y; n1e.y = ev.z; n1e.z = ev.w; \
  hv = vc; he = ev; \
}

    for (int kg = ke; kg > ke - 1024; kg -= 8) {
      if (l == 63 && w < 2 && kg >= kb + 255) {
        const int need = max(kg - 6, kb + 256);
        while (__hip_atomic_load(&Pb[w + 1], __ATOMIC_ACQUIRE,
                                 __HIP_MEMORY_SCOPE_WORKGROUP) > need) {}
      }
      BSTEP(0, V1, K1, F1, T0, T1) BSTEP(1, V0, K0, F0, T1, T0)
      BSTEP(2, V3, K3, F3, T0, T1) BSTEP(3, V2, K2, F2, T1, T0)
      BSTEP(4, V1, K1, F1, T0, T1) BSTEP(5, V0, K0, F0, T1, T0)
      BSTEP(6, V3, K3, F3, T0, T1) BSTEP(7, V2, K2, F2, T1, T0)
      if (l == 0 && w > 0) lds_release_store(&Pb[w], kg - 7);
    }
#undef BSTEP
#undef BCELL
  }
}

}  // namespace

extern "C" void kernel_launch(void* const* d_in, const int* in_sizes, int n_in,
                              void* d_out, int out_size, void* d_ws, size_t ws_size,
                              hipStream_t stream) {
  const float* hx = (const float*)d_in[0];
  const float* hy = (const float*)d_in[1];
  const float* Wm = (const float*)d_in[2];
  const float* bm = (const float*)d_in[3];
  const float* Wg = (const float*)d_in[4];
  const float* bg = (const float*)d_in[5];

  float* aln   = (float*)d_out;
  float* theta = aln + (size_t)BB * L2E;
  float* A     = theta + (size_t)BB * L2E;

  unsigned short* hxb = (unsigned short*)d_ws;
  unsigned short* hyb = hxb + (size_t)6144 * 512;
  unsigned short* Wmb = hyb + (size_t)6144 * 512;
  unsigned short* Wgb = Wmb + (size_t)512 * 512;
  unsigned short* Zb  = Wgb + (size_t)512 * 512;
  unsigned* TAc = (unsigned*)d_ws;
  float* Vr = (float*)d_ws + (size_t)BB * LDIAG;
  unsigned short* Edc = (unsigned short*)(Vr + (size_t)BB * (1536 * LL));

  const int nX = 6144 * 512, nW = 512 * 512;
  tobf16<<<(nX / 4 + 255) / 256, 256, 0, stream>>>(hx, hxb, nX);
  tobf16<<<(nX / 4 + 255) / 256, 256, 0, stream>>>(hy, hyb, nX);
  tobf16<<<(nW / 4 + 255) / 256, 256, 0, stream>>>(Wm, Wmb, nW);
  tobf16<<<(nW / 4 + 255) / 256, 256, 0, stream>>>(Wg, Wgb, nW);

  mfma_linear<<<dim3(4, 48, 4), 256, 0, stream>>>(hxb, Wmb, bm, bg, Zb);
  mfma_logits<<<dim3(6, 6, 16), 256, 0, stream>>>(Zb, theta, A);

  row2diag<<<dim3(LL / 64, LL / 64, BB), 256, 0, stream>>>(theta, A, TAc);
  nw_fused<<<dim3(BB), 192, 0, stream>>>(TAc, Vr, Edc);
  diag2row<<<dim3(LL / 64, LL / 64, BB), 256, 0, stream>>>(Edc, aln);
}

// Round 17
// 1361.352 us; speedup vs baseline: 1.7500x; 1.2174x over previous
//
#include <hip/hip_runtime.h>
#include <hip/hip_bf16.h>
#include <math.h>

namespace {

constexpr int BB = 8;
constexpr int LL = 768;
constexpr int DD = 512;
constexpr int L2E = LL * LL;
constexpr int LDIAG = L2E + 8192;
constexpr float NEGF = -1e9f;

typedef __attribute__((ext_vector_type(8))) short bf16x8;
typedef __attribute__((ext_vector_type(8))) unsigned short u16x8;
typedef __attribute__((ext_vector_type(4))) float f32x4;

__device__ __forceinline__ float softplus_f(float x) {
  return x > 0.f ? x + log1pf(expf(-x)) : log1pf(expf(x));
}
__device__ __forceinline__ float logsigmoid_f(float x) {
  return x > 0.f ? -log1pf(expf(-x)) : x - log1pf(expf(x));
}

__device__ __forceinline__ float bf_lo(unsigned u) { return __uint_as_float(u << 16); }
__device__ __forceinline__ float bf_hi(unsigned u) { return __uint_as_float(u & 0xffff0000u); }

__device__ __forceinline__ int lofs(int s) { return (s > LL - 1) ? (s - (LL - 1)) : 0; }

__device__ __forceinline__ int Dmap(int s) {
  if (s <= LL - 1) {
    const int m = s >> 2, i = s & 3;
    const int c = (i == 0) ? 4 : (i == 1) ? 8 : (i == 2) ? 16 : 24;
    return 8 * m * m + (20 + 4 * i) * m + c;
  }
  const int q = (s - LL) >> 2, i = (s - LL) & 3;
  const int base = 298757 + 3092 * q - 8 * q * q;
  const int off = (i == 0) ? 0 : (i == 1) ? (773 - 4 * q)
                : (i == 2) ? (1546 - 8 * q) : (2315 - 12 * q);
  return base + off;
}
__device__ __forceinline__ int dDa(int s) {
  if (s < LL - 1) return s + 4 + ((-s) & 3);
  if (s == LL - 1) return 773;
  return 1539 - s + ((s + 2) & 3);
}
__device__ __forceinline__ int dIa(int s) { return dDa(s) - ((s >= LL - 1) ? 1 : 0); }

// -------- fp32 -> bf16 convert --------
__global__ __launch_bounds__(256) void tobf16(
    const float* __restrict__ src, unsigned short* __restrict__ dst, int n) {
  const int i = (blockIdx.x * 256 + threadIdx.x) * 4;
  if (i < n) {
    const float4 v = *(const float4*)(src + i);
    ushort4 o;
    o.x = __bfloat16_as_ushort(__float2bfloat16(v.x));
    o.y = __bfloat16_as_ushort(__float2bfloat16(v.y));
    o.z = __bfloat16_as_ushort(__float2bfloat16(v.z));
    o.w = __bfloat16_as_ushort(__float2bfloat16(v.w));
    *(ushort4*)(dst + i) = o;
  }
}

// -------- MFMA GEMM 1 --------
__global__ __launch_bounds__(256) void mfma_linear(
    const unsigned short* __restrict__ Xb, const unsigned short* __restrict__ Wb,
    const float* __restrict__ bm, const float* __restrict__ bg,
    unsigned short* __restrict__ Zb) {
  __shared__ unsigned short As[128][32];
  __shared__ unsigned short Bs[128][32];
  const int which = blockIdx.z;
  const unsigned short* X = Xb + (size_t)(which & 1) * (6144 * 512);
  const unsigned short* W = Wb + (size_t)(which >> 1) * (512 * 512);
  const float* bias = (which >= 2) ? bg : bm;
  unsigned short* out = Zb + (size_t)which * (6144 * 512);
  const int row0 = blockIdx.y * 128, col0 = blockIdx.x * 128;
  const int t = threadIdx.x, wv = t >> 6, l = t & 63;
  const int wm = (wv >> 1) * 64, wn = (wv & 1) * 64;

  f32x4 acc[4][4] = {};
  for (int k0 = 0; k0 < 512; k0 += 32) {
#pragma unroll
    for (int c = t; c < 512; c += 256) {
      const int rowi = c >> 2, seg = (c & 3) << 3;
      *(u16x8*)&As[rowi][seg] = *(const u16x8*)&X[(size_t)(row0 + rowi) * 512 + k0 + seg];
      *(u16x8*)&Bs[rowi][seg] = *(const u16x8*)&W[(size_t)(col0 + rowi) * 512 + k0 + seg];
    }
    __syncthreads();
    bf16x8 af[4], bfr[4];
#pragma unroll
    for (int f = 0; f < 4; ++f) {
      af[f]  = *(const bf16x8*)&As[wm + f * 16 + (l & 15)][(l >> 4) << 3];
      bfr[f] = *(const bf16x8*)&Bs[wn + f * 16 + (l & 15)][(l >> 4) << 3];
    }
#pragma unroll
    for (int fm = 0; fm < 4; ++fm)
#pragma unroll
      for (int fn = 0; fn < 4; ++fn)
        acc[fm][fn] = __builtin_amdgcn_mfma_f32_16x16x32_bf16(
            af[fm], bfr[fn], acc[fm][fn], 0, 0, 0);
    __syncthreads();
  }
#pragma unroll
  for (int fm = 0; fm < 4; ++fm) {
    const int rbase = row0 + wm + fm * 16 + ((l >> 4) << 2);
#pragma unroll
    for (int fn = 0; fn < 4; ++fn) {
      const int col = col0 + wn + fn * 16 + (l & 15);
      const float bv = bias[col];
      const f32x4 v = acc[fm][fn];
#pragma unroll
      for (int j = 0; j < 4; ++j)
        out[(size_t)(rbase + j) * 512 + col] =
            __bfloat16_as_ushort(__float2bfloat16(v[j] + bv));
    }
  }
}

// -------- MFMA GEMM 2 --------
__global__ __launch_bounds__(256) void mfma_logits(
    const unsigned short* __restrict__ Zb,
    float* __restrict__ theta, float* __restrict__ Aout) {
  __shared__ unsigned short As[128][32];
  __shared__ unsigned short Bs[128][32];
  const int bz = blockIdx.z;
  const int b = bz >> 1, w = bz & 1;
  const unsigned short* X = Zb + (size_t)(w ? 2 : 0) * (6144 * 512) + (size_t)b * (768 * 512);
  const unsigned short* Y = Zb + (size_t)(w ? 3 : 1) * (6144 * 512) + (size_t)b * (768 * 512);
  float* out = (w ? Aout : theta) + (size_t)b * L2E;
  const int row0 = blockIdx.y * 128, col0 = blockIdx.x * 128;
  const int t = threadIdx.x, wv = t >> 6, l = t & 63;
  const int wm = (wv >> 1) * 64, wn = (wv & 1) * 64;

  f32x4 acc[4][4] = {};
  for (int k0 = 0; k0 < 512; k0 += 32) {
#pragma unroll
    for (int c = t; c < 512; c += 256) {
      const int rowi = c >> 2, seg = (c & 3) << 3;
      *(u16x8*)&As[rowi][seg] = *(const u16x8*)&X[(size_t)(row0 + rowi) * 512 + k0 + seg];
      *(u16x8*)&Bs[rowi][seg] = *(const u16x8*)&Y[(size_t)(col0 + rowi) * 512 + k0 + seg];
    }
    __syncthreads();
    bf16x8 af[4], bfr[4];
#pragma unroll
    for (int f = 0; f < 4; ++f) {
      af[f]  = *(const bf16x8*)&As[wm + f * 16 + (l & 15)][(l >> 4) << 3];
      bfr[f] = *(const bf16x8*)&Bs[wn + f * 16 + (l & 15)][(l >> 4) << 3];
    }
#pragma unroll
    for (int fm = 0; fm < 4; ++fm)
#pragma unroll
      for (int fn = 0; fn < 4; ++fn)
        acc[fm][fn] = __builtin_amdgcn_mfma_f32_16x16x32_bf16(
            af[fm], bfr[fn], acc[fm][fn], 0, 0, 0);
    __syncthreads();
  }
#pragma unroll
  for (int fm = 0; fm < 4; ++fm) {
    const int rbase = row0 + wm + fm * 16 + ((l >> 4) << 2);
#pragma unroll
    for (int fn = 0; fn < 4; ++fn) {
      const int col = col0 + wn + fn * 16 + (l & 15);
      const f32x4 v = acc[fm][fn];
#pragma unroll
      for (int j = 0; j < 4; ++j)
        out[(size_t)(rbase + j) * LL + col] = w ? logsigmoid_f(v[j]) : softplus_f(v[j]);
    }
  }
}

// -------- row-major theta,A -> packed bf16x2 compact-aligned diag --------
__global__ __launch_bounds__(256) void row2diag(
    const float* __restrict__ theta, const float* __restrict__ A,
    unsigned* __restrict__ TAc) {
  __shared__ float tT[64 * 66];
  __shared__ float tA[64 * 66];
  const int b = blockIdx.z;
  const float* inT = theta + (size_t)b * L2E;
  const float* inA = A + (size_t)b * L2E;
  unsigned* out = TAc + (size_t)b * LDIAG;
  const int r0 = blockIdx.y * 64, c0 = blockIdx.x * 64;
  const int t = threadIdx.x, lane = t & 63, grp = t >> 6;
  for (int it = 0; it < 16; ++it) {
    const int rr = it * 4 + grp;
    tT[rr * 66 + lane] = inT[(size_t)(r0 + rr) * LL + c0 + lane];
    tA[rr * 66 + lane] = inA[(size_t)(r0 + rr) * LL + c0 + lane];
  }
  __syncthreads();
  for (int si = grp; si < 127; si += 4) {
    const int s = r0 + c0 + si;
    const int rlo = max(r0, s - c0 - 63);
    const int rhi = min(r0 + 63, s - c0);
    const int base = Dmap(s) - lofs(s);
    const int r = rlo + lane;
    if (r <= rhi) {
      const int ii = (r - r0) * 66 + (s - r - c0);
      const unsigned ut = __bfloat16_as_ushort(__float2bfloat16(tT[ii]));
      const unsigned ua = __bfloat16_as_ushort(__float2bfloat16(tA[ii]));
      out[base + r] = (ua << 16) | ut;
    }
  }
}

// -------- compact-aligned bf16 E -> row-major fp32 (aln) --------
__global__ __launch_bounds__(256) void diag2row(
    const unsigned short* __restrict__ Edc, float* __restrict__ aln) {
  __shared__ float tile[64 * 66];
  const int b = blockIdx.z;
  const int r0 = blockIdx.y * 64;
  const int c0 = blockIdx.x * 64;
  const unsigned short* E = Edc + (size_t)b * LDIAG;
  float* out = aln + (size_t)b * L2E;
  const int t = threadIdx.x;
  const int lane = t & 63;
  const int grp = t >> 6;
  for (int si = grp; si < 127; si += 4) {
    const int s = r0 + c0 + si;
    const int rlo = max(r0, s - c0 - 63);
    const int rhi = min(r0 + 63, s - c0);
    const int base = Dmap(s) - lofs(s);
    const int r = rlo + lane;
    if (r <= rhi) {
      tile[(r - r0) * 66 + (s - r - c0)] =
          __uint_as_float(((unsigned)E[base + r]) << 16);
    }
  }
  __syncthreads();
  for (int it = 0; it < 16; ++it) {
    const int rr = it * 4 + grp;
    out[(size_t)(r0 + rr) * LL + c0 + lane] = tile[rr * 66 + lane];
  }
}

__device__ __forceinline__ void lds_release_store(int* p, int v) {
  asm volatile("s_waitcnt lgkmcnt(0)" ::: "memory");
  __hip_atomic_store(p, v, __ATOMIC_RELAXED, __HIP_MEMORY_SCOPE_WORKGROUP);
}

// -------- NW forward: R=2 (2 rows/lane), 6 waves/batch, 1 batch/CU ----------
__global__ __launch_bounds__(384, 1) void nw_fwd(
    const unsigned* __restrict__ TAc, float* __restrict__ Vr) {
  __shared__ int Pf[8];
  __shared__ float BvF[5][1024];

  const int b = blockIdx.x;
  const unsigned* TA = TAc + (size_t)b * LDIAG;
  float* V = Vr + (size_t)b * (1536 * LL);

  const int tl = threadIdx.x;
  const int w = tl >> 6, l = tl & 63;
  const int rowb = 2 * tl;
  const int kb = 128 * w + 2;

  if (tl < 8) Pf[tl] = 0;
  __syncthreads();

  uint2 q0, q1, q2, q3;
  {
    int s0;
    s0 = kb - 2; q2 = *(const uint2*)(TA + (Dmap(s0) + rowb - lofs(s0)));
    s0 = kb - 1; q3 = *(const uint2*)(TA + (Dmap(s0) + rowb - lofs(s0)));
    s0 = kb;     q0 = *(const uint2*)(TA + (Dmap(s0) + rowb - lofs(s0)));
    s0 = kb + 1; q1 = *(const uint2*)(TA + (Dmap(s0) + rowb - lofs(s0)));
  }
  int sL = kb + 2;
  int iL = Dmap(sL) + rowb - lofs(sL);
  int iS = (kb - 2) * LL + rowb;
  float2 p1 = make_float2(NEGF, NEGF);
  float2 p2 = p1;
  float rvh = NEGF;
  float pv1 = NEGF;  // own vv.y (second row) of previous step

#define FSTEP(U, Q) { \
  const int k = kg + (U); \
  float rv = __shfl_up(pv1, 1); \
  if (l == 0) rv = (w == 0) ? NEGF : BvF[w - 1][min(k - kb + 127, 1023)]; \
  float rdg = rvh; \
  if (l == 0 && w == 0) rdg = (k == 2) ? 0.f : NEGF; \
  const int d = k - rowb - 2; \
  float2 vv; \
  { const float av = bf_hi(Q.x), tv = bf_lo(Q.x); \
    const float lft = av + p1.x, up = av + rv; \
    const float mx = fmaxf(rdg, fmaxf(lft, up)); \
    const float val = tv + mx + __logf(__expf(rdg - mx) + __expf(lft - mx) + __expf(up - mx)); \
    vv.x = ((unsigned)d <= 767u) ? val : NEGF; } \
  { const float av = bf_hi(Q.y), tv = bf_lo(Q.y); \
    const float lft = av + p1.y, up = av + p1.x; \
    const float mx = fmaxf(p2.x, fmaxf(lft, up)); \
    const float val = tv + mx + __logf(__expf(p2.x - mx) + __expf(lft - mx) + __expf(up - mx)); \
    vv.y = ((unsigned)(d - 1) <= 767u) ? val : NEGF; } \
  Q = *(const uint2*)(TA + iL); \
  iL += dIa(sL); ++sL; \
  *(float2*)(V + iS) = vv; \
  iS += LL; \
  if (l == 63 && w < 5) BvF[w][k - kb] = vv.y; \
  pv1 = vv.y; \
  rvh = rv; \
  p2 = p1; p1 = vv; \
}

  for (int kg = kb; kg < kb + 896; kg += 8) {
    if (l == 0 && w > 0 && kg < kb + 768) {
      const int need = min(kg + 6, kb + 766);
      while (__hip_atomic_load(&Pf[w - 1], __ATOMIC_ACQUIRE,
                               __HIP_MEMORY_SCOPE_WORKGROUP) < need) {}
    }
    FSTEP(0, q2) FSTEP(1, q3) FSTEP(2, q0) FSTEP(3, q1)
    FSTEP(4, q2) FSTEP(5, q3) FSTEP(6, q0) FSTEP(7, q1)
    if (l == 63 && w < 5) lds_release_store(&Pf[w], kg + 7);
  }
#undef FSTEP
}

// -------- NW backward: R=2 (2 rows/lane), 6 waves/batch, 1 batch/CU ---------
__global__ __launch_bounds__(384, 1) void nw_bwd(
    const unsigned* __restrict__ TAc, const float* __restrict__ Vr,
    unsigned short* __restrict__ Edc) {
  __shared__ int Pb[8];
  __shared__ float Bv2[5][1024];
  __shared__ float Be2[5][1024];

  const int b = blockIdx.x;
  const unsigned* TA = TAc + (size_t)b * LDIAG;
  const float* V = Vr + (size_t)b * (1536 * LL);
  unsigned short* Eo = Edc + (size_t)b * LDIAG;

  const int tl = threadIdx.x;
  const int w = tl >> 6, l = tl & 63;
  const int rowb = 2 * tl;
  const int kb = 128 * w + 2;
  const int ke = kb + 895;

  if (tl < 8) Pb[tl] = 0x7fffffff;
  __syncthreads();

  float2 V0, V1, V2, V3;
  uint2 K0, K1, K2, K3;
  unsigned F0, F1, F2, F3;
  {
    int sv, sk, ik;
    sv = ke - 2; V1 = *(const float2*)(V + (sv * LL + rowb));
    sk = ke - 1; ik = Dmap(sk) + rowb - lofs(sk);
    K1 = *(const uint2*)(TA + ik); F1 = TA[ik + 2];
    sv = ke - 3; V0 = *(const float2*)(V + (sv * LL + rowb));
    sk = ke - 2; ik = Dmap(sk) + rowb - lofs(sk);
    K0 = *(const uint2*)(TA + ik); F0 = TA[ik + 2];
    sv = ke - 4; V3 = *(const float2*)(V + (sv * LL + rowb));
    sk = ke - 3; ik = Dmap(sk) + rowb - lofs(sk);
    K3 = *(const uint2*)(TA + ik); F3 = TA[ik + 2];
    sv = ke - 5; V2 = *(const float2*)(V + (sv * LL + rowb));
    sk = ke - 4; ik = Dmap(sk) + rowb - lofs(sk);
    K2 = *(const uint2*)(TA + ik); F2 = TA[ik + 2];
  }
  int iV = (ke - 6) * LL + rowb;
  int sK1s = ke - 5;
  int iK1 = Dmap(sK1s) + rowb - lofs(sK1s);
  float2 T0, T1;
  {
    const int j0 = Dmap(ke) + rowb - lofs(ke);
    T0 = make_float2(bf_lo(TA[j0 + 1]), bf_lo(TA[j0 + 2]));
    T1 = make_float2(0.f, 0.f);
  }
  int sE = ke - 2;
  int iE = Dmap(sE) + rowb - lofs(sE);
  float2 n1v = {}, n1e = {}, n2v = {}, n2e = {}, hv = {}, he = {};
  float pv0 = 0.f, pe0 = 0.f;

#define BCELL(VCr, DO, ILT, N2Vr, N2Er, TKr, S1a, S1b, N1Vr, N1Er, HVr, HEr, OUT) { \
  const bool ok  = (unsigned)(d - (DO)) <= 767u; \
  const bool jlt = (d - (DO)) < 767; \
  float acc = 0.f; \
  if ((ILT) && jlt) acc += N2Er * __expf(VCr - N2Vr + TKr); \
  if (jlt)          acc += HEr * __expf(bf_hi(S1a) + VCr - HVr + bf_lo(S1a)); \
  if ((ILT))        acc += N1Er * __expf(bf_hi(S1b) + VCr - N1Vr + bf_lo(S1b)); \
  OUT = ok ? acc : 0.f; }

#define BSTEP(U, SV, SK, SF, TRD, TWR) { \
  const int k = kg - (U); \
  { float nv1 = __shfl_down(pv0, 1); \
    float ne1 = __shfl_down(pe0, 1); \
    if (l == 63) { \
      if (w < 5) { const int bi2 = min(ke - k + 127, 1023); nv1 = Bv2[w][bi2]; ne1 = Be2[w][bi2]; } \
      else { nv1 = 0.f; ne1 = 0.f; } } \
    n1v.y = nv1; n1e.y = ne1; } \
  const int d = k - rowb - 2; \
  unsigned third = __shfl_down(SK.x, 1); \
  if (l == 63) third = SF; \
  const float2 vc = SV; \
  float2 ev; \
  BCELL(vc.x, 0, true, n2v.x, n2e.x, TRD.x, SK.x, SK.y, n1v.x, n1e.x, hv.x, he.x, ev.x) \
  BCELL(vc.y, 1, (tl != 383), n2v.y, n2e.y, TRD.y, SK.y, third, n1v.y, n1e.y, hv.y, he.y, ev.y) \
  if (k == 2 * LL && tl == 383) ev.y = 1.f; \
  TWR.x = bf_lo(SK.y); TWR.y = bf_lo(third); \
  SV = *(const float2*)(V + max(iV, 0)); \
  iV -= LL; \
  { const int ic = max(iK1, 0); \
    SK = *(const uint2*)(TA + ic); \
    if (l == 63) SF = TA[ic + 2]; \
    iK1 -= dIa(sK1s - 1); --sK1s; } \
  if ((unsigned)d <= 768u) { \
    ushort2 st; \
    st.x = __bfloat16_as_ushort(__float2bfloat16(ev.x)); \
    st.y = __bfloat16_as_ushort(__float2bfloat16(ev.y)); \
    *(ushort2*)(Eo + iE) = st; } \
  iE -= dIa(sE - 1); --sE; \
  if (l == 0 && w > 0) { Bv2[w - 1][ke - k] = vc.x; Be2[w - 1][ke - k] = ev.x; } \
  pv0 = vc.x; pe0 = ev.x; \
  n2v = n1v; n2e = n1e; \
  n1v.x = vc.y; n1e.x = ev.y; \
  hv = vc; he = ev; \
}

  for (int kg = ke; kg > ke - 896; kg -= 8) {
    if (l == 63 && w < 5 && kg >= kb + 127) {
      const int need = max(kg - 6, kb + 128);
      while (__hip_atomic_load(&Pb[w + 1], __ATOMIC_ACQUIRE,
                               __HIP_MEMORY_SCOPE_WORKGROUP) > need) {}
    }
    BSTEP(0, V1, K1, F1, T0, T1) BSTEP(1, V0, K0, F0, T1, T0)
    BSTEP(2, V3, K3, F3, T0, T1) BSTEP(3, V2, K2, F2, T1, T0)
    BSTEP(4, V1, K1, F1, T0, T1) BSTEP(5, V0, K0, F0, T1, T0)
    BSTEP(6, V3, K3, F3, T0, T1) BSTEP(7, V2, K2, F2, T1, T0)
    if (l == 0 && w > 0) lds_release_store(&Pb[w], kg - 7);
  }
#undef BSTEP
#undef BCELL
}

}  // namespace

extern "C" void kernel_launch(void* const* d_in, const int* in_sizes, int n_in,
                              void* d_out, int out_size, void* d_ws, size_t ws_size,
                              hipStream_t stream) {
  const float* hx = (const float*)d_in[0];
  const float* hy = (const float*)d_in[1];
  const float* Wm = (const float*)d_in[2];
  const float* bm = (const float*)d_in[3];
  const float* Wg = (const float*)d_in[4];
  const float* bg = (const float*)d_in[5];

  float* aln   = (float*)d_out;
  float* theta = aln + (size_t)BB * L2E;
  float* A     = theta + (size_t)BB * L2E;

  unsigned short* hxb = (unsigned short*)d_ws;
  unsigned short* hyb = hxb + (size_t)6144 * 512;
  unsigned short* Wmb = hyb + (size_t)6144 * 512;
  unsigned short* Wgb = Wmb + (size_t)512 * 512;
  unsigned short* Zb  = Wgb + (size_t)512 * 512;
  unsigned* TAc = (unsigned*)d_ws;
  float* Vr = (float*)d_ws + (size_t)BB * LDIAG;
  unsigned short* Edc = (unsigned short*)(Vr + (size_t)BB * (1536 * LL));

  const int nX = 6144 * 512, nW = 512 * 512;
  tobf16<<<(nX / 4 + 255) / 256, 256, 0, stream>>>(hx, hxb, nX);
  tobf16<<<(nX / 4 + 255) / 256, 256, 0, stream>>>(hy, hyb, nX);
  tobf16<<<(nW / 4 + 255) / 256, 256, 0, stream>>>(Wm, Wmb, nW);
  tobf16<<<(nW / 4 + 255) / 256, 256, 0, stream>>>(Wg, Wgb, nW);

  mfma_linear<<<dim3(4, 48, 4), 256, 0, stream>>>(hxb, Wmb, bm, bg, Zb);
  mfma_logits<<<dim3(6, 6, 16), 256, 0, stream>>>(Zb, theta, A);

  row2diag<<<dim3(LL / 64, LL / 64, BB), 256, 0, stream>>>(theta, A, TAc);
  nw_fwd<<<dim3(BB), 384, 0, stream>>>(TAc, Vr);
  nw_bwd<<<dim3(BB), 384, 0, stream>>>(TAc, Vr, Edc);
  diag2row<<<dim3(LL / 64, LL / 64, BB), 256, 0, stream>>>(Edc, aln);
}

// Round 18
// 1284.089 us; speedup vs baseline: 1.8553x; 1.0602x over previous
//
#include <hip/hip_runtime.h>
#include <hip/hip_bf16.h>
#include <math.h>

namespace {

constexpr int BB = 8;
constexpr int LL = 768;
constexpr int DD = 512;
constexpr int L2E = LL * LL;
constexpr int LDIAG = L2E + 8192;
constexpr float NEGF = -1e9f;

typedef __attribute__((ext_vector_type(8))) short bf16x8;
typedef __attribute__((ext_vector_type(8))) unsigned short u16x8;
typedef __attribute__((ext_vector_type(4))) float f32x4;

__device__ __forceinline__ float softplus_f(float x) {
  return x > 0.f ? x + log1pf(expf(-x)) : log1pf(expf(x));
}
__device__ __forceinline__ float logsigmoid_f(float x) {
  return x > 0.f ? -log1pf(expf(-x)) : x - log1pf(expf(x));
}

__device__ __forceinline__ float bf_lo(unsigned u) { return __uint_as_float(u << 16); }
__device__ __forceinline__ float bf_hi(unsigned u) { return __uint_as_float(u & 0xffff0000u); }
__device__ __forceinline__ float us2f(unsigned short u) {
  return __uint_as_float(((unsigned)u) << 16);
}

__device__ __forceinline__ int lofs(int s) { return (s > LL - 1) ? (s - (LL - 1)) : 0; }

__device__ __forceinline__ int Dmap(int s) {
  if (s <= LL - 1) {
    const int m = s >> 2, i = s & 3;
    const int c = (i == 0) ? 4 : (i == 1) ? 8 : (i == 2) ? 16 : 24;
    return 8 * m * m + (20 + 4 * i) * m + c;
  }
  const int q = (s - LL) >> 2, i = (s - LL) & 3;
  const int base = 298757 + 3092 * q - 8 * q * q;
  const int off = (i == 0) ? 0 : (i == 1) ? (773 - 4 * q)
                : (i == 2) ? (1546 - 8 * q) : (2315 - 12 * q);
  return base + off;
}
__device__ __forceinline__ int dDa(int s) {
  if (s < LL - 1) return s + 4 + ((-s) & 3);
  if (s == LL - 1) return 773;
  return 1539 - s + ((s + 2) & 3);
}
__device__ __forceinline__ int dIa(int s) { return dDa(s) - ((s >= LL - 1) ? 1 : 0); }

// -------- fp32 -> bf16 convert --------
__global__ __launch_bounds__(256) void tobf16(
    const float* __restrict__ src, unsigned short* __restrict__ dst, int n) {
  const int i = (blockIdx.x * 256 + threadIdx.x) * 4;
  if (i < n) {
    const float4 v = *(const float4*)(src + i);
    ushort4 o;
    o.x = __bfloat16_as_ushort(__float2bfloat16(v.x));
    o.y = __bfloat16_as_ushort(__float2bfloat16(v.y));
    o.z = __bfloat16_as_ushort(__float2bfloat16(v.z));
    o.w = __bfloat16_as_ushort(__float2bfloat16(v.w));
    *(ushort4*)(dst + i) = o;
  }
}

// -------- MFMA GEMM 1 --------
__global__ __launch_bounds__(256) void mfma_linear(
    const unsigned short* __restrict__ Xb, const unsigned short* __restrict__ Wb,
    const float* __restrict__ bm, const float* __restrict__ bg,
    unsigned short* __restrict__ Zb) {
  __shared__ unsigned short As[128][32];
  __shared__ unsigned short Bs[128][32];
  const int which = blockIdx.z;
  const unsigned short* X = Xb + (size_t)(which & 1) * (6144 * 512);
  const unsigned short* W = Wb + (size_t)(which >> 1) * (512 * 512);
  const float* bias = (which >= 2) ? bg : bm;
  unsigned short* out = Zb + (size_t)which * (6144 * 512);
  const int row0 = blockIdx.y * 128, col0 = blockIdx.x * 128;
  const int t = threadIdx.x, wv = t >> 6, l = t & 63;
  const int wm = (wv >> 1) * 64, wn = (wv & 1) * 64;

  f32x4 acc[4][4] = {};
  for (int k0 = 0; k0 < 512; k0 += 32) {
#pragma unroll
    for (int c = t; c < 512; c += 256) {
      const int rowi = c >> 2, seg = (c & 3) << 3;
      *(u16x8*)&As[rowi][seg] = *(const u16x8*)&X[(size_t)(row0 + rowi) * 512 + k0 + seg];
      *(u16x8*)&Bs[rowi][seg] = *(const u16x8*)&W[(size_t)(col0 + rowi) * 512 + k0 + seg];
    }
    __syncthreads();
    bf16x8 af[4], bfr[4];
#pragma unroll
    for (int f = 0; f < 4; ++f) {
      af[f]  = *(const bf16x8*)&As[wm + f * 16 + (l & 15)][(l >> 4) << 3];
      bfr[f] = *(const bf16x8*)&Bs[wn + f * 16 + (l & 15)][(l >> 4) << 3];
    }
#pragma unroll
    for (int fm = 0; fm < 4; ++fm)
#pragma unroll
      for (int fn = 0; fn < 4; ++fn)
        acc[fm][fn] = __builtin_amdgcn_mfma_f32_16x16x32_bf16(
            af[fm], bfr[fn], acc[fm][fn], 0, 0, 0);
    __syncthreads();
  }
#pragma unroll
  for (int fm = 0; fm < 4; ++fm) {
    const int rbase = row0 + wm + fm * 16 + ((l >> 4) << 2);
#pragma unroll
    for (int fn = 0; fn < 4; ++fn) {
      const int col = col0 + wn + fn * 16 + (l & 15);
      const float bv = bias[col];
      const f32x4 v = acc[fm][fn];
#pragma unroll
      for (int j = 0; j < 4; ++j)
        out[(size_t)(rbase + j) * 512 + col] =
            __bfloat16_as_ushort(__float2bfloat16(v[j] + bv));
    }
  }
}

// -------- MFMA GEMM 2 --------
__global__ __launch_bounds__(256) void mfma_logits(
    const unsigned short* __restrict__ Zb,
    float* __restrict__ theta, float* __restrict__ Aout) {
  __shared__ unsigned short As[128][32];
  __shared__ unsigned short Bs[128][32];
  const int bz = blockIdx.z;
  const int b = bz >> 1, w = bz & 1;
  const unsigned short* X = Zb + (size_t)(w ? 2 : 0) * (6144 * 512) + (size_t)b * (768 * 512);
  const unsigned short* Y = Zb + (size_t)(w ? 3 : 1) * (6144 * 512) + (size_t)b * (768 * 512);
  float* out = (w ? Aout : theta) + (size_t)b * L2E;
  const int row0 = blockIdx.y * 128, col0 = blockIdx.x * 128;
  const int t = threadIdx.x, wv = t >> 6, l = t & 63;
  const int wm = (wv >> 1) * 64, wn = (wv & 1) * 64;

  f32x4 acc[4][4] = {};
  for (int k0 = 0; k0 < 512; k0 += 32) {
#pragma unroll
    for (int c = t; c < 512; c += 256) {
      const int rowi = c >> 2, seg = (c & 3) << 3;
      *(u16x8*)&As[rowi][seg] = *(const u16x8*)&X[(size_t)(row0 + rowi) * 512 + k0 + seg];
      *(u16x8*)&Bs[rowi][seg] = *(const u16x8*)&Y[(size_t)(col0 + rowi) * 512 + k0 + seg];
    }
    __syncthreads();
    bf16x8 af[4], bfr[4];
#pragma unroll
    for (int f = 0; f < 4; ++f) {
      af[f]  = *(const bf16x8*)&As[wm + f * 16 + (l & 15)][(l >> 4) << 3];
      bfr[f] = *(const bf16x8*)&Bs[wn + f * 16 + (l & 15)][(l >> 4) << 3];
    }
#pragma unroll
    for (int fm = 0; fm < 4; ++fm)
#pragma unroll
      for (int fn = 0; fn < 4; ++fn)
        acc[fm][fn] = __builtin_amdgcn_mfma_f32_16x16x32_bf16(
            af[fm], bfr[fn], acc[fm][fn], 0, 0, 0);
    __syncthreads();
  }
#pragma unroll
  for (int fm = 0; fm < 4; ++fm) {
    const int rbase = row0 + wm + fm * 16 + ((l >> 4) << 2);
#pragma unroll
    for (int fn = 0; fn < 4; ++fn) {
      const int col = col0 + wn + fn * 16 + (l & 15);
      const f32x4 v = acc[fm][fn];
#pragma unroll
      for (int j = 0; j < 4; ++j)
        out[(size_t)(rbase + j) * LL + col] = w ? logsigmoid_f(v[j]) : softplus_f(v[j]);
    }
  }
}

// -------- row-major theta,A -> packed bf16x2 compact-aligned diag --------
__global__ __launch_bounds__(256) void row2diag(
    const float* __restrict__ theta, const float* __restrict__ A,
    unsigned* __restrict__ TAc) {
  __shared__ float tT[64 * 66];
  __shared__ float tA[64 * 66];
  const int b = blockIdx.z;
  const float* inT = theta + (size_t)b * L2E;
  const float* inA = A + (size_t)b * L2E;
  unsigned* out = TAc + (size_t)b * LDIAG;
  const int r0 = blockIdx.y * 64, c0 = blockIdx.x * 64;
  const int t = threadIdx.x, lane = t & 63, grp = t >> 6;
  for (int it = 0; it < 16; ++it) {
    const int rr = it * 4 + grp;
    tT[rr * 66 + lane] = inT[(size_t)(r0 + rr) * LL + c0 + lane];
    tA[rr * 66 + lane] = inA[(size_t)(r0 + rr) * LL + c0 + lane];
  }
  __syncthreads();
  for (int si = grp; si < 127; si += 4) {
    const int s = r0 + c0 + si;
    const int rlo = max(r0, s - c0 - 63);
    const int rhi = min(r0 + 63, s - c0);
    const int base = Dmap(s) - lofs(s);
    const int r = rlo + lane;
    if (r <= rhi) {
      const int ii = (r - r0) * 66 + (s - r - c0);
      const unsigned ut = __bfloat16_as_ushort(__float2bfloat16(tT[ii]));
      const unsigned ua = __bfloat16_as_ushort(__float2bfloat16(tA[ii]));
      out[base + r] = (ua << 16) | ut;
    }
  }
}

// -------- compact-aligned bf16 E -> row-major fp32 (aln) --------
__global__ __launch_bounds__(256) void diag2row(
    const unsigned short* __restrict__ Edc, float* __restrict__ aln) {
  __shared__ float tile[64 * 66];
  const int b = blockIdx.z;
  const int r0 = blockIdx.y * 64;
  const int c0 = blockIdx.x * 64;
  const unsigned short* E = Edc + (size_t)b * LDIAG;
  float* out = aln + (size_t)b * L2E;
  const int t = threadIdx.x;
  const int lane = t & 63;
  const int grp = t >> 6;
  for (int si = grp; si < 127; si += 4) {
    const int s = r0 + c0 + si;
    const int rlo = max(r0, s - c0 - 63);
    const int rhi = min(r0 + 63, s - c0);
    const int base = Dmap(s) - lofs(s);
    const int r = rlo + lane;
    if (r <= rhi) {
      tile[(r - r0) * 66 + (s - r - c0)] =
          __uint_as_float(((unsigned)E[base + r]) << 16);
    }
  }
  __syncthreads();
  for (int it = 0; it < 16; ++it) {
    const int rr = it * 4 + grp;
    out[(size_t)(r0 + rr) * LL + c0 + lane] = tile[rr * 66 + lane];
  }
}

__device__ __forceinline__ void lds_release_store(int* p, int v) {
  asm volatile("s_waitcnt lgkmcnt(0)" ::: "memory");
  __hip_atomic_store(p, v, __ATOMIC_RELAXED, __HIP_MEMORY_SCOPE_WORKGROUP);
}

// -------- NW forward: R=1 (1 row/lane), 12 waves/batch, 1 batch/CU ----------
__global__ __launch_bounds__(768, 1) void nw_fwd(
    const unsigned* __restrict__ TAc, float* __restrict__ Vr) {
  __shared__ int Pf[16];
  __shared__ float BvF[11][832];

  const int b = blockIdx.x;
  const unsigned* TA = TAc + (size_t)b * LDIAG;
  float* V = Vr + (size_t)b * (1536 * LL);

  const int tl = threadIdx.x;
  const int w = tl >> 6, l = tl & 63;
  const int kb = 64 * w + 2;

  if (tl < 16) Pf[tl] = 0;
  __syncthreads();

  unsigned q0, q1, q2, q3;
  {
    int s0;
    s0 = kb - 2; q2 = TA[Dmap(s0) + tl - lofs(s0)];
    s0 = kb - 1; q3 = TA[Dmap(s0) + tl - lofs(s0)];
    s0 = kb;     q0 = TA[Dmap(s0) + tl - lofs(s0)];
    s0 = kb + 1; q1 = TA[Dmap(s0) + tl - lofs(s0)];
  }
  int sL = kb + 2;
  int iL = Dmap(sL) + tl - lofs(sL);
  int iS = (kb - 2) * LL + tl;
  float p1 = NEGF;
  float rvh = NEGF;
  float pv = NEGF;

#define FSTEP(U, Q) { \
  const int k = kg + (U); \
  float rv = __shfl_up(pv, 1); \
  if (l == 0) rv = (w == 0) ? NEGF : BvF[w - 1][min(k - kb + 63, 831)]; \
  float rdg = rvh; \
  if (l == 0 && w == 0) rdg = (k == 2) ? 0.f : NEGF; \
  const int d = k - tl - 2; \
  const float av = bf_hi(Q), tv = bf_lo(Q); \
  const float lft = av + p1, up = av + rv; \
  const float mx = fmaxf(rdg, fmaxf(lft, up)); \
  const float val = tv + mx + __logf(__expf(rdg - mx) + __expf(lft - mx) + __expf(up - mx)); \
  const float vv = ((unsigned)d <= 767u) ? val : NEGF; \
  Q = TA[iL]; \
  iL += dIa(sL); ++sL; \
  V[iS] = vv; \
  iS += LL; \
  if (l == 63 && w < 11) BvF[w][k - kb] = vv; \
  pv = vv; \
  rvh = rv; \
  p1 = vv; \
}

  for (int kg = kb; kg < kb + 832; kg += 8) {
    if (l == 0 && w > 0 && kg < kb + 768) {
      const int need = min(kg + 6, kb + 766);
      while (__hip_atomic_load(&Pf[w - 1], __ATOMIC_ACQUIRE,
                               __HIP_MEMORY_SCOPE_WORKGROUP) < need) {}
    }
    FSTEP(0, q2) FSTEP(1, q3) FSTEP(2, q0) FSTEP(3, q1)
    FSTEP(4, q2) FSTEP(5, q3) FSTEP(6, q0) FSTEP(7, q1)
    if (l == 63 && w < 11) lds_release_store(&Pf[w], kg + 7);
  }
#undef FSTEP
}

// -------- NW backward: R=1 (1 row/lane), 12 waves/batch, 1 batch/CU ---------
__global__ __launch_bounds__(768, 1) void nw_bwd(
    const unsigned* __restrict__ TAc, const float* __restrict__ Vr,
    unsigned short* __restrict__ Edc) {
  __shared__ int Pb[16];
  __shared__ float Bv2[11][832];
  __shared__ unsigned short Be2[11][832];

  const int b = blockIdx.x;
  const unsigned* TA = TAc + (size_t)b * LDIAG;
  const float* V = Vr + (size_t)b * (1536 * LL);
  unsigned short* Eo = Edc + (size_t)b * LDIAG;

  const int tl = threadIdx.x;
  const int w = tl >> 6, l = tl & 63;
  const int kb = 64 * w + 2;
  const int ke = kb + 831;

  if (tl < 16) Pb[tl] = 0x7fffffff;
  __syncthreads();

  float V0, V1, V2, V3;
  unsigned K0, K1, K2, K3;
  unsigned F0, F1, F2, F3;
  {
    int sv, sk, ik;
    sv = ke - 2; V1 = V[sv * LL + tl];
    sk = ke - 1; ik = Dmap(sk) + tl - lofs(sk);
    K1 = TA[ik]; F1 = TA[ik + 1];
    sv = ke - 3; V0 = V[sv * LL + tl];
    sk = ke - 2; ik = Dmap(sk) + tl - lofs(sk);
    K0 = TA[ik]; F0 = TA[ik + 1];
    sv = ke - 4; V3 = V[sv * LL + tl];
    sk = ke - 3; ik = Dmap(sk) + tl - lofs(sk);
    K3 = TA[ik]; F3 = TA[ik + 1];
    sv = ke - 5; V2 = V[sv * LL + tl];
    sk = ke - 4; ik = Dmap(sk) + tl - lofs(sk);
    K2 = TA[ik]; F2 = TA[ik + 1];
  }
  int iV = (ke - 6) * LL + tl;
  int sK1s = ke - 5;
  int iK1 = Dmap(sK1s) + tl - lofs(sK1s);
  float T0, T1;
  {
    const int j0 = Dmap(ke) + tl - lofs(ke);
    T0 = bf_lo(TA[j0 + 1]);
    T1 = 0.f;
  }
  int sE = ke - 2;
  int iE = Dmap(sE) + tl - lofs(sE);
  float n1v = 0.f, n1e = 0.f, n2v = 0.f, n2e = 0.f, hv = 0.f, he = 0.f;
  float pv0 = 0.f, pe0 = 0.f;
  const bool ILT = (tl != 767);

#define BSTEP(U, SV, SK, SF, TRD, TWR) { \
  const int k = kg - (U); \
  { float nv = __shfl_down(pv0, 1); \
    float ne = __shfl_down(pe0, 1); \
    if (l == 63) { \
      if (w < 11) { const int bi2 = min(64 * w + 896 - k, 831); \
        nv = Bv2[w][bi2]; ne = us2f(Be2[w][bi2]); } \
      else { nv = 0.f; ne = 0.f; } } \
    n1v = nv; n1e = ne; } \
  const int d = k - tl - 2; \
  unsigned third = __shfl_down(SK, 1); \
  if (l == 63) third = SF; \
  const float vc = SV; \
  float ev; \
  { const bool ok  = (unsigned)d <= 767u; \
    const bool jlt = d < 767; \
    float acc = 0.f; \
    if (ILT && jlt) acc += n2e * __expf(vc - n2v + TRD); \
    if (jlt)        acc += he * __expf(bf_hi(SK) + vc - hv + bf_lo(SK)); \
    if (ILT)        acc += n1e * __expf(bf_hi(third) + vc - n1v + bf_lo(third)); \
    ev = ok ? acc : 0.f; } \
  if (k == 2 * LL && tl == 767) ev = 1.f; \
  TWR = bf_lo(third); \
  SV = V[max(iV, 0)]; \
  iV -= LL; \
  { const int ic = max(iK1, 0); \
    SK = TA[ic]; \
    if (l == 63) SF = TA[ic + 1]; \
    iK1 -= dIa(sK1s - 1); --sK1s; } \
  if ((unsigned)d <= 767u) Eo[iE] = __bfloat16_as_ushort(__float2bfloat16(ev)); \
  iE -= dIa(sE - 1); --sE; \
  if (l == 0 && w > 0) { \
    Bv2[w - 1][ke - k] = vc; \
    Be2[w - 1][ke - k] = __bfloat16_as_ushort(__float2bfloat16(ev)); } \
  pv0 = vc; pe0 = ev; \
  n2v = n1v; n2e = n1e; \
  hv = vc; he = ev; \
}

  for (int kg = ke; kg > ke - 832; kg -= 8) {
    if (l == 63 && w < 11 && kg >= 64 * w + 65) {
      const int need = max(kg - 6, 64 * w + 66);
      while (__hip_atomic_load(&Pb[w + 1], __ATOMIC_ACQUIRE,
                               __HIP_MEMORY_SCOPE_WORKGROUP) > need) {}
    }
    BSTEP(0, V1, K1, F1, T0, T1) BSTEP(1, V0, K0, F0, T1, T0)
    BSTEP(2, V3, K3, F3, T0, T1) BSTEP(3, V2, K2, F2, T1, T0)
    BSTEP(4, V1, K1, F1, T0, T1) BSTEP(5, V0, K0, F0, T1, T0)
    BSTEP(6, V3, K3, F3, T0, T1) BSTEP(7, V2, K2, F2, T1, T0)
    if (l == 0 && w > 0) lds_release_store(&Pb[w], kg - 7);
  }
#undef BSTEP
}

}  // namespace

extern "C" void kernel_launch(void* const* d_in, const int* in_sizes, int n_in,
                              void* d_out, int out_size, void* d_ws, size_t ws_size,
                              hipStream_t stream) {
  const float* hx = (const float*)d_in[0];
  const float* hy = (const float*)d_in[1];
  const float* Wm = (const float*)d_in[2];
  const float* bm = (const float*)d_in[3];
  const float* Wg = (const float*)d_in[4];
  const float* bg = (const float*)d_in[5];

  float* aln   = (float*)d_out;
  float* theta = aln + (size_t)BB * L2E;
  float* A     = theta + (size_t)BB * L2E;

  unsigned short* hxb = (unsigned short*)d_ws;
  unsigned short* hyb = hxb + (size_t)6144 * 512;
  unsigned short* Wmb = hyb + (size_t)6144 * 512;
  unsigned short* Wgb = Wmb + (size_t)512 * 512;
  unsigned short* Zb  = Wgb + (size_t)512 * 512;
  unsigned* TAc = (unsigned*)d_ws;
  float* Vr = (float*)d_ws + (size_t)BB * LDIAG;
  unsigned short* Edc = (unsigned short*)(Vr + (size_t)BB * (1536 * LL));

  const int nX = 6144 * 512, nW = 512 * 512;
  tobf16<<<(nX / 4 + 255) / 256, 256, 0, stream>>>(hx, hxb, nX);
  tobf16<<<(nX / 4 + 255) / 256, 256, 0, stream>>>(hy, hyb, nX);
  tobf16<<<(nW / 4 + 255) / 256, 256, 0, stream>>>(Wm, Wmb, nW);
  tobf16<<<(nW / 4 + 255) / 256, 256, 0, stream>>>(Wg, Wgb, nW);

  mfma_linear<<<dim3(4, 48, 4), 256, 0, stream>>>(hxb, Wmb, bm, bg, Zb);
  mfma_logits<<<dim3(6, 6, 16), 256, 0, stream>>>(Zb, theta, A);

  row2diag<<<dim3(LL / 64, LL / 64, BB), 256, 0, stream>>>(theta, A, TAc);
  nw_fwd<<<dim3(BB), 768, 0, stream>>>(TAc, Vr);
  nw_bwd<<<dim3(BB), 768, 0, stream>>>(TAc, Vr, Edc);
  diag2row<<<dim3(LL / 64, LL / 64, BB), 256, 0, stream>>>(Edc, aln);
}